// Round 8
// baseline (2477.717 us; speedup 1.0000x reference)
//
#include <hip/hip_runtime.h>
#include <math.h>

#define N_NODES 50000
#define N_EDGES 100000
#define H 768
#define NH 12
#define HD 64
#define NG 64
#define NC 10
#define H2 384

typedef __attribute__((ext_vector_type(8))) short          bfrag;   // 8 bf16 (4 VGPR)
typedef __attribute__((ext_vector_type(4))) float          ffrag;   // MFMA acc

// ---------------- static device scratch ----------------
__device__ float          g_bufA[(size_t)N_NODES * H];
__device__ float          g_bufB[(size_t)N_NODES * H];
__device__ unsigned short g_ah[(size_t)N_NODES * H];   // activation hi bf16
__device__ unsigned short g_al[(size_t)N_NODES * H];   // activation lo bf16
__device__ unsigned short g_wh[H * H];                 // weight^T hi bf16 [N][K]
__device__ unsigned short g_wl[H * H];                 // weight^T lo bf16
__device__ float          g_dinv[N_NODES];
__device__ int            g_degi[N_NODES];
__device__ int            g_cursor[N_NODES];
__device__ int            g_rowptr[N_NODES + 1];
__device__ int            g_csrsrc[N_EDGES];
__device__ float          g_aS[(size_t)N_NODES * NH];
__device__ float          g_aD[(size_t)N_NODES * NH];
__device__ float          g_pool[NG * H];
__device__ float          g_zb[NG * H2];

__device__ inline int clampi(int v, int hi) { return (v < 0) ? 0 : (v >= hi ? hi - 1 : v); }

__device__ inline unsigned short bf16rn(float f) {
    unsigned u = __float_as_uint(f);
    unsigned r = u + 0x7fffu + ((u >> 16) & 1u);   // RNE; inputs finite
    return (unsigned short)(r >> 16);
}
__device__ inline float bf16f(unsigned short h) { return __uint_as_float((unsigned)h << 16); }

// async global->LDS, 16B per lane: lane i writes lds_base + i*16 (wave-uniform base)
__device__ inline void gload_lds16(const unsigned short* g, unsigned short* s) {
    __builtin_amdgcn_global_load_lds(
        (const __attribute__((address_space(1))) void*)g,
        (__attribute__((address_space(3))) void*)s, 16, 0, 0);
}

// ---------------- CSR build ----------------
__global__ void fill_i32(int* p, int n, int v) {
    int i = blockIdx.x * blockDim.x + threadIdx.x;
    if (i < n) p[i] = v;
}

__global__ void count_deg(const int* __restrict__ dst, int* __restrict__ degi) {
    int e = blockIdx.x * blockDim.x + threadIdx.x;
    if (e < N_EDGES) atomicAdd(&degi[clampi(dst[e], N_NODES)], 1);
}

__global__ void dinv_k(const int* __restrict__ degi, float* __restrict__ dinv) {
    int i = blockIdx.x * blockDim.x + threadIdx.x;
    if (i < N_NODES) dinv[i] = rsqrtf((float)degi[i] + 1.0f);   // +1 = self-loop
}

__global__ __launch_bounds__(1024) void scan_rowptr(const int* __restrict__ degi,
                                                    int* __restrict__ rowptr,
                                                    int* __restrict__ cursor) {
    __shared__ int buf[1024];
    __shared__ int carry;
    int tid = threadIdx.x;
    if (tid == 0) carry = 0;
    __syncthreads();
    for (int base = 0; base < N_NODES; base += 1024) {
        int idx = base + tid;
        int v = (idx < N_NODES) ? degi[idx] : 0;
        buf[tid] = v;
        __syncthreads();
        for (int off = 1; off < 1024; off <<= 1) {
            int t = (tid >= off) ? buf[tid - off] : 0;
            __syncthreads();
            buf[tid] += t;
            __syncthreads();
        }
        if (idx < N_NODES) {
            int excl = buf[tid] - v + carry;
            rowptr[idx] = excl;
            cursor[idx] = excl;
        }
        int total = buf[1023];
        __syncthreads();
        if (tid == 0) carry += total;
        __syncthreads();
    }
    if (tid == 0) rowptr[N_NODES] = carry;
}

__global__ void bin_edges(const int* __restrict__ src, const int* __restrict__ dst,
                          int* __restrict__ cursor, int* __restrict__ csrsrc) {
    int e = blockIdx.x * blockDim.x + threadIdx.x;
    if (e >= N_EDGES) return;
    int d = clampi(dst[e], N_NODES);
    int pos = atomicAdd(&cursor[d], 1);
    if (pos >= 0 && pos < N_EDGES) csrsrc[pos] = clampi(src[e], N_NODES);
}

// ---------------- GEMM: x@w1 (K=3) ----------------
__global__ void gemm_k3(const float* __restrict__ x, const float* __restrict__ w,
                        float* __restrict__ out) {
    int idx = blockIdx.x * blockDim.x + threadIdx.x;
    if (idx >= N_NODES * H) return;
    int n = idx / H, j = idx % H;
    float x0 = x[n*3], x1 = x[n*3+1], x2 = x[n*3+2];
    out[idx] = x0 * w[j] + x1 * w[H + j] + x2 * w[2*H + j];
}

// weights: w[K][N] fp32 -> transposed hi/lo bf16 [N][K]
__global__ void split_wT(const float* __restrict__ w, unsigned short* __restrict__ hi,
                         unsigned short* __restrict__ lo) {
    int idx = blockIdx.x * blockDim.x + threadIdx.x;   // over H*H
    if (idx >= H * H) return;
    int n = idx % H, k = idx / H;                      // read coalesced in n
    float v = w[(size_t)k * H + n];
    unsigned short h = bf16rn(v);
    hi[(size_t)n * H + k] = h;
    lo[(size_t)n * H + k] = bf16rn(v - bf16f(h));
}

// ---------------- bf16x3 MFMA GEMM ----------------
// C[M,768] = A[M,768] @ W; A,W pre-split bf16 hi/lo; W transposed [N][K].
// 128x128 tile, 256 threads (4 waves), wave = 64x64 via 4x4 of 16x16x32 MFMA.
// Round-7 evidence: LDS pipe (~105 us/dispatch of ds_read+lds-write) exceeded
// the 74-us MFMA floor -> B (2.4 MB, L2-resident) now bypasses LDS: fragments
// loaded per-wave straight from global. Only A is staged (global_load_lds,
// double-buffered 2x16 KB = 32 KB -> ~3 blocks/CU).
// If asf/adf nonnull (GAT layers), the epilogue also emits alpha_src/alpha_dst:
// each block's 128 cols = exactly 2 complete heads, so a per-lane 4-col dot +
// 16-lane shfl_xor reduce gives final aS/aD (no atomics, no extra kernel).
__global__ __launch_bounds__(256) void gemm_bf16x3(const unsigned short* __restrict__ ah,
                                                   const unsigned short* __restrict__ al,
                                                   const unsigned short* __restrict__ bth,
                                                   const unsigned short* __restrict__ btl,
                                                   float* __restrict__ C, int M,
                                                   const float* __restrict__ asf,
                                                   const float* __restrict__ adf,
                                                   float* __restrict__ aS,
                                                   float* __restrict__ aD) {
    __shared__ unsigned short sA[2][2][128 * 32];   // [buf][hi/lo][rows x 32k]
    int tid = threadIdx.x;
    int wave = tid >> 6, lane = tid & 63;
    int quad = lane >> 4, l16 = lane & 15;

    int id = blockIdx.x;
    int x = id & 7;            // XCD slot (round-robin); strips grouped per-XCD
    int s = id >> 3;
    int strip = x + 8 * (s / 6);
    int colt = s % 6;
    if (strip >= (N_NODES + 127) / 128) return;
    int row0 = strip * 128, col0 = colt * 128;
    int wr = (wave >> 1) * 64, wc = (wave & 1) * 64;

    // A staging: 16 segs (8 hi + 8 lo), each 16 rows x 32 k = 1 KB = one
    // wave-instruction of global_load_lds. Wave w stages segs 4w..4w+3.
    int rr = lane >> 2, kc = (lane & 3) << 3;
    const unsigned short* gp[4];
    int sel[4], soff[4];
    #pragma unroll
    for (int k = 0; k < 4; k++) {
        int sg = wave * 4 + k;               // 0..15
        int hilo = (sg >> 3);                // 0=hi, 1=lo
        int r = row0 + (sg & 7) * 16 + rr;
        if (r >= M) r = M - 1;               // clamped rows feed unstored C rows
        gp[k] = (hilo ? al : ah) + (size_t)r * H + kc;
        sel[k] = hilo;
        soff[k] = (sg & 7) * 512;
    }

    // B fragment base offsets (per lane): column (col0+wc+j*16+l16), k at quad*8
    size_t boff[4];
    #pragma unroll
    for (int j = 0; j < 4; j++)
        boff[j] = (size_t)(col0 + wc + j * 16 + l16) * H + quad * 8;

    ffrag acc[4][4];
    #pragma unroll
    for (int i = 0; i < 4; i++)
        #pragma unroll
        for (int j = 0; j < 4; j++) { ffrag z = {0.f, 0.f, 0.f, 0.f}; acc[i][j] = z; }

    // prologue: stage A k-tile 0 into buf 0
    #pragma unroll
    for (int k = 0; k < 4; k++)
        gload_lds16(gp[k], &sA[0][sel[k]][soff[k]]);

    #pragma unroll 1
    for (int kt = 0; kt < H / 32; kt++) {
        int cur = kt & 1;
        __syncthreads();   // A(kt) resident in buf[cur]
        // prefetch A(kt+1) into other buffer; drains only at NEXT barrier
        if (kt + 1 < H / 32) {
            int koff = (kt + 1) * 32;
            #pragma unroll
            for (int k = 0; k < 4; k++)
                gload_lds16(gp[k] + koff, &sA[cur ^ 1][sel[k]][soff[k]]);
        }

        // B fragments direct from global (L1/L2-hit; latency overlaps ds_reads)
        bfrag fbh[4], fbl[4];
        #pragma unroll
        for (int j = 0; j < 4; j++) {
            fbh[j] = *reinterpret_cast<const bfrag*>(bth + boff[j] + kt * 32);
            fbl[j] = *reinterpret_cast<const bfrag*>(btl + boff[j] + kt * 32);
        }
        // A fragments from LDS
        const unsigned short* pAh = sA[cur][0];
        const unsigned short* pAl = sA[cur][1];
        bfrag fah[4], fal[4];
        #pragma unroll
        for (int i = 0; i < 4; i++) {
            int r = wr + i * 16 + l16;
            fah[i] = *reinterpret_cast<const bfrag*>(&pAh[r * 32 + quad * 8]);
            fal[i] = *reinterpret_cast<const bfrag*>(&pAl[r * 32 + quad * 8]);
        }
        #pragma unroll
        for (int i = 0; i < 4; i++)
            #pragma unroll
            for (int j = 0; j < 4; j++) {
                acc[i][j] = __builtin_amdgcn_mfma_f32_16x16x32_bf16(fah[i], fbh[j], acc[i][j], 0, 0, 0);
                acc[i][j] = __builtin_amdgcn_mfma_f32_16x16x32_bf16(fah[i], fbl[j], acc[i][j], 0, 0, 0);
                acc[i][j] = __builtin_amdgcn_mfma_f32_16x16x32_bf16(fal[i], fbh[j], acc[i][j], 0, 0, 0);
            }
    }

    // epilogue: C/D layout col=lane&15, row=quad*4+reg (m89-verified)
    #pragma unroll
    for (int i = 0; i < 4; i++)
        #pragma unroll
        for (int r = 0; r < 4; r++) {
            int row = row0 + wr + i * 16 + quad * 4 + r;
            if (row >= M) continue;
            #pragma unroll
            for (int j = 0; j < 4; j++)
                C[(size_t)row * H + col0 + wc + j * 16 + l16] = acc[i][j][r];
        }

    // fused GAT alpha: this wave covers one full head (64 cols) for 64 rows
    if (asf) {
        int head = (col0 + wc) >> 6;
        float as_c[4], ad_c[4];
        #pragma unroll
        for (int j = 0; j < 4; j++) {
            int col = col0 + wc + j * 16 + l16;
            as_c[j] = asf[col];
            ad_c[j] = adf[col];
        }
        #pragma unroll
        for (int i = 0; i < 4; i++)
            #pragma unroll
            for (int r = 0; r < 4; r++) {
                float ps = 0.f, pd = 0.f;
                #pragma unroll
                for (int j = 0; j < 4; j++) {
                    ps += acc[i][j][r] * as_c[j];
                    pd += acc[i][j][r] * ad_c[j];
                }
                ps += __shfl_xor(ps, 1);  pd += __shfl_xor(pd, 1);
                ps += __shfl_xor(ps, 2);  pd += __shfl_xor(pd, 2);
                ps += __shfl_xor(ps, 4);  pd += __shfl_xor(pd, 4);
                ps += __shfl_xor(ps, 8);  pd += __shfl_xor(pd, 8);
                int row = row0 + wr + i * 16 + quad * 4 + r;
                if (l16 == 0 && row < M) {
                    aS[row * NH + head] = ps;
                    aD[row * NH + head] = pd;
                }
            }
    }
}

// ---------------- fused GCN gather (self + edges + bias + relu + bf16 split) ----
__global__ void gcn_gather(const int* __restrict__ rowptr, const int* __restrict__ csrsrc,
                           const float* __restrict__ h, const float* __restrict__ dinv,
                           const float* __restrict__ bias,
                           unsigned short* __restrict__ hi, unsigned short* __restrict__ lo) {
    int d = blockIdx.x;
    int t = threadIdx.x;
    float dd = dinv[d];
    float4 v = ((const float4*)(h + (size_t)d * H))[t];
    float c = dd * dd;
    float4 acc; acc.x = v.x * c; acc.y = v.y * c; acc.z = v.z * c; acc.w = v.w * c;
    int beg = rowptr[d], end = rowptr[d + 1];
    for (int i = beg; i < end; i++) {
        int s = csrsrc[i];
        float cc = dinv[s] * dd;
        float4 u = ((const float4*)(h + (size_t)s * H))[t];
        acc.x += u.x * cc; acc.y += u.y * cc; acc.z += u.z * cc; acc.w += u.w * cc;
    }
    float4 b = ((const float4*)bias)[t];
    acc.x = fmaxf(acc.x + b.x, 0.f); acc.y = fmaxf(acc.y + b.y, 0.f);
    acc.z = fmaxf(acc.z + b.z, 0.f); acc.w = fmaxf(acc.w + b.w, 0.f);
    ushort4 h4, l4;
    h4.x = bf16rn(acc.x); l4.x = bf16rn(acc.x - bf16f(h4.x));
    h4.y = bf16rn(acc.y); l4.y = bf16rn(acc.y - bf16f(h4.y));
    h4.z = bf16rn(acc.z); l4.z = bf16rn(acc.z - bf16f(h4.z));
    h4.w = bf16rn(acc.w); l4.w = bf16rn(acc.w - bf16f(h4.w));
    ((ushort4*)(hi + (size_t)d * H))[t] = h4;
    ((ushort4*)(lo + (size_t)d * H))[t] = l4;
}

__device__ inline float lrelu(float v) { return (v > 0.f) ? v : 0.2f * v; }

// fused softmax + weighted aggregation + bias (+relu); one block per dst node.
__global__ void gat_gather(const int* __restrict__ rowptr, const int* __restrict__ csrsrc,
                           const float* __restrict__ h, const float* __restrict__ aS,
                           const float* __restrict__ aD, const float* __restrict__ bias,
                           float* __restrict__ out,
                           unsigned short* __restrict__ hi, unsigned short* __restrict__ lo,
                           int relu) {
    int d = blockIdx.x;
    int t = threadIdx.x;
    int hh = t >> 4;
    int beg = rowptr[d], end = rowptr[d + 1];
    float adv = aD[d * NH + hh];
    float eself = lrelu(aS[d * NH + hh] + adv);
    float m = eself;
    for (int i = beg; i < end; i++)
        m = fmaxf(m, lrelu(aS[csrsrc[i] * NH + hh] + adv));
    float ssum = __expf(eself - m);
    for (int i = beg; i < end; i++)
        ssum += __expf(lrelu(aS[csrsrc[i] * NH + hh] + adv) - m);
    float inv = 1.0f / ssum;
    float cself = __expf(eself - m) * inv;
    float4 v = ((const float4*)(h + (size_t)d * H))[t];
    float4 acc; acc.x = v.x * cself; acc.y = v.y * cself; acc.z = v.z * cself; acc.w = v.w * cself;
    for (int i = beg; i < end; i++) {
        int s = csrsrc[i];
        float c = __expf(lrelu(aS[s * NH + hh] + adv) - m) * inv;
        float4 u = ((const float4*)(h + (size_t)s * H))[t];
        acc.x += u.x * c; acc.y += u.y * c; acc.z += u.z * c; acc.w += u.w * c;
    }
    float4 b = ((const float4*)bias)[t];
    acc.x += b.x; acc.y += b.y; acc.z += b.z; acc.w += b.w;
    if (relu) {
        acc.x = fmaxf(acc.x, 0.f); acc.y = fmaxf(acc.y, 0.f);
        acc.z = fmaxf(acc.z, 0.f); acc.w = fmaxf(acc.w, 0.f);
    }
    if (hi) {
        ushort4 h4, l4;
        h4.x = bf16rn(acc.x); l4.x = bf16rn(acc.x - bf16f(h4.x));
        h4.y = bf16rn(acc.y); l4.y = bf16rn(acc.y - bf16f(h4.y));
        h4.z = bf16rn(acc.z); l4.z = bf16rn(acc.z - bf16f(h4.z));
        h4.w = bf16rn(acc.w); l4.w = bf16rn(acc.w - bf16f(h4.w));
        ((ushort4*)(hi + (size_t)d * H))[t] = h4;
        ((ushort4*)(lo + (size_t)d * H))[t] = l4;
    } else {
        ((float4*)(out + (size_t)d * H))[t] = acc;
    }
}

// ---------------- pooling (batch is sorted) + classifier ----------------
__device__ inline int lower_bound_i(const int* b, int n, int key) {
    int lo = 0, hi = n;
    while (lo < hi) { int mid = (lo + hi) >> 1; if (b[mid] < key) lo = mid + 1; else hi = mid; }
    return lo;
}

__global__ void pool_graph(const int* __restrict__ batch, const float* __restrict__ h,
                           float* __restrict__ pool) {
    int g = blockIdx.x;   // NG blocks, 192 threads
    int t = threadIdx.x;
    int lo = lower_bound_i(batch, N_NODES, g);
    int hi = lower_bound_i(batch, N_NODES, g + 1);
    float4 a0 = {0,0,0,0}, a1 = {0,0,0,0}, a2 = {0,0,0,0}, a3 = {0,0,0,0};
    int n = lo;
    for (; n + 3 < hi; n += 4) {
        float4 v0 = ((const float4*)(h + (size_t)(n+0) * H))[t];
        float4 v1 = ((const float4*)(h + (size_t)(n+1) * H))[t];
        float4 v2 = ((const float4*)(h + (size_t)(n+2) * H))[t];
        float4 v3 = ((const float4*)(h + (size_t)(n+3) * H))[t];
        a0.x += v0.x; a0.y += v0.y; a0.z += v0.z; a0.w += v0.w;
        a1.x += v1.x; a1.y += v1.y; a1.z += v1.z; a1.w += v1.w;
        a2.x += v2.x; a2.y += v2.y; a2.z += v2.z; a2.w += v2.w;
        a3.x += v3.x; a3.y += v3.y; a3.z += v3.z; a3.w += v3.w;
    }
    for (; n < hi; n++) {
        float4 v = ((const float4*)(h + (size_t)n * H))[t];
        a0.x += v.x; a0.y += v.y; a0.z += v.z; a0.w += v.w;
    }
    float inv = 1.0f / fmaxf((float)(hi - lo), 1.0f);
    float4 o;
    o.x = (a0.x + a1.x + a2.x + a3.x) * inv;
    o.y = (a0.y + a1.y + a2.y + a3.y) * inv;
    o.z = (a0.z + a1.z + a2.z + a3.z) * inv;
    o.w = (a0.w + a1.w + a2.w + a3.w) * inv;
    ((float4*)(pool + (size_t)g * H))[t] = o;
}

__global__ void mlp1(const float* __restrict__ g, const float* __restrict__ w,
                     const float* __restrict__ b, float* __restrict__ z) {
    int idx = blockIdx.x * blockDim.x + threadIdx.x;
    if (idx >= NG * H2) return;
    int gg = idx / H2, j = idx % H2;
    const float* gp = g + (size_t)gg * H;
    float acc = b[j];
    for (int k = 0; k < H; k++) acc += gp[k] * w[(size_t)k * H2 + j];
    z[idx] = fmaxf(acc, 0.f);
}

__global__ void mlp2(const float* __restrict__ z, const float* __restrict__ w,
                     const float* __restrict__ b, float* __restrict__ out) {
    int idx = blockIdx.x * blockDim.x + threadIdx.x;
    if (idx >= NG * NC) return;
    int gg = idx / NC, c = idx % NC;
    const float* zp = z + (size_t)gg * H2;
    float acc = b[c];
    for (int k = 0; k < H2; k++) acc += zp[k] * w[(size_t)k * NC + c];
    out[idx] = acc;
}

// ---------------- launch ----------------
extern "C" void kernel_launch(void* const* d_in, const int* in_sizes, int n_in,
                              void* d_out, int out_size, void* d_ws, size_t ws_size,
                              hipStream_t stream) {
    (void)d_ws; (void)ws_size;
    const float* x     = (const float*)d_in[0];
    const int*   ei    = (const int*)d_in[1];
    const int*   batch = (const int*)d_in[2];
    const float* w1  = (const float*)d_in[3];  const float* b1  = (const float*)d_in[4];
    const float* w2  = (const float*)d_in[5];  const float* b2  = (const float*)d_in[6];
    const float* w3  = (const float*)d_in[7];  const float* b3  = (const float*)d_in[8];
    const float* wg1 = (const float*)d_in[9];  const float* as1 = (const float*)d_in[10];
    const float* ad1 = (const float*)d_in[11]; const float* bg1 = (const float*)d_in[12];
    const float* wg2 = (const float*)d_in[13]; const float* as2 = (const float*)d_in[14];
    const float* ad2 = (const float*)d_in[15]; const float* bg2 = (const float*)d_in[16];
    const float* wc1 = (const float*)d_in[17]; const float* bc1 = (const float*)d_in[18];
    const float* wc2 = (const float*)d_in[19]; const float* bc2 = (const float*)d_in[20];

    const int* srcp = ei;            // edge_index[0]
    const int* dstp = ei + N_EDGES;  // edge_index[1]

    float *bufA, *bufB, *dinv, *aS, *aD, *pool, *zb;
    unsigned short *ah, *al, *wh, *wl;
    int *degi, *cursor, *rowptr, *csrsrc;
    hipGetSymbolAddress((void**)&bufA,   HIP_SYMBOL(g_bufA));
    hipGetSymbolAddress((void**)&bufB,   HIP_SYMBOL(g_bufB));
    hipGetSymbolAddress((void**)&ah,     HIP_SYMBOL(g_ah));
    hipGetSymbolAddress((void**)&al,     HIP_SYMBOL(g_al));
    hipGetSymbolAddress((void**)&wh,     HIP_SYMBOL(g_wh));
    hipGetSymbolAddress((void**)&wl,     HIP_SYMBOL(g_wl));
    hipGetSymbolAddress((void**)&dinv,   HIP_SYMBOL(g_dinv));
    hipGetSymbolAddress((void**)&degi,   HIP_SYMBOL(g_degi));
    hipGetSymbolAddress((void**)&cursor, HIP_SYMBOL(g_cursor));
    hipGetSymbolAddress((void**)&rowptr, HIP_SYMBOL(g_rowptr));
    hipGetSymbolAddress((void**)&csrsrc, HIP_SYMBOL(g_csrsrc));
    hipGetSymbolAddress((void**)&aS,     HIP_SYMBOL(g_aS));
    hipGetSymbolAddress((void**)&aD,     HIP_SYMBOL(g_aD));
    hipGetSymbolAddress((void**)&pool,   HIP_SYMBOL(g_pool));
    hipGetSymbolAddress((void**)&zb,     HIP_SYMBOL(g_zb));

    auto cdiv = [](int a, int b) { return (a + b - 1) / b; };
    // strips padded to 8-aligned (392) x 6 col tiles; kernel guards spill
    int ggrid = 8 * cdiv(cdiv(N_NODES, 128), 8) * (H / 128);   // 2352

    // ---- CSR build (per call; inputs re-restored each launch) ----
    fill_i32<<<cdiv(N_NODES,256),256,0,stream>>>(degi, N_NODES, 0);
    count_deg<<<cdiv(N_EDGES,256),256,0,stream>>>(dstp, degi);
    dinv_k<<<cdiv(N_NODES,256),256,0,stream>>>(degi, dinv);
    scan_rowptr<<<1,1024,0,stream>>>(degi, rowptr, cursor);
    bin_edges<<<cdiv(N_EDGES,256),256,0,stream>>>(srcp, dstp, cursor, csrsrc);

    // ---- GCN1 (K=3 GEMM stays fp32 vector) ----
    gemm_k3<<<cdiv(N_NODES*H,256),256,0,stream>>>(x, w1, bufA);
    gcn_gather<<<N_NODES,192,0,stream>>>(rowptr, csrsrc, bufA, dinv, b1, ah, al);

    // ---- GCN2 ----
    split_wT<<<cdiv(H*H,256),256,0,stream>>>(w2, wh, wl);
    gemm_bf16x3<<<ggrid,256,0,stream>>>(ah, al, wh, wl, bufA, N_NODES,
                                        (const float*)nullptr, (const float*)nullptr,
                                        (float*)nullptr, (float*)nullptr);
    gcn_gather<<<N_NODES,192,0,stream>>>(rowptr, csrsrc, bufA, dinv, b2, ah, al);

    // ---- GCN3 ----
    split_wT<<<cdiv(H*H,256),256,0,stream>>>(w3, wh, wl);
    gemm_bf16x3<<<ggrid,256,0,stream>>>(ah, al, wh, wl, bufA, N_NODES,
                                        (const float*)nullptr, (const float*)nullptr,
                                        (float*)nullptr, (float*)nullptr);
    gcn_gather<<<N_NODES,192,0,stream>>>(rowptr, csrsrc, bufA, dinv, b3, ah, al);

    // ---- GAT1 (alpha fused into GEMM epilogue) ----
    split_wT<<<cdiv(H*H,256),256,0,stream>>>(wg1, wh, wl);
    gemm_bf16x3<<<ggrid,256,0,stream>>>(ah, al, wh, wl, bufA, N_NODES,
                                        as1, ad1, aS, aD);
    gat_gather<<<N_NODES,192,0,stream>>>(rowptr, csrsrc, bufA, aS, aD, bg1,
                                         (float*)nullptr, ah, al, 1);

    // ---- GAT2 (no relu; fp32 out for pooling) ----
    split_wT<<<cdiv(H*H,256),256,0,stream>>>(wg2, wh, wl);
    gemm_bf16x3<<<ggrid,256,0,stream>>>(ah, al, wh, wl, bufA, N_NODES,
                                        as2, ad2, aS, aD);
    gat_gather<<<N_NODES,192,0,stream>>>(rowptr, csrsrc, bufA, aS, aD, bg2,
                                         bufB, (unsigned short*)nullptr, (unsigned short*)nullptr, 0);

    // ---- pool + classifier ----
    pool_graph<<<NG,192,0,stream>>>(batch, bufB, pool);
    mlp1<<<cdiv(NG*H2,256),256,0,stream>>>(pool, wc1, bc1, zb);
    mlp2<<<cdiv(NG*NC,64),64,0,stream>>>(zb, wc2, bc2, (float*)d_out);
}

// Round 9
// 2188.370 us; speedup vs baseline: 1.1322x; 1.1322x over previous
//
#include <hip/hip_runtime.h>
#include <math.h>

#define N_NODES 50000
#define N_EDGES 100000
#define H 768
#define NH 12
#define HD 64
#define NG 64
#define NC 10
#define H2 384

typedef __attribute__((ext_vector_type(8))) short          bfrag;   // 8 bf16 (4 VGPR)
typedef __attribute__((ext_vector_type(4))) float          ffrag;   // MFMA acc

// ---------------- static device scratch ----------------
__device__ float          g_bufA[(size_t)N_NODES * H];
__device__ float          g_bufB[(size_t)N_NODES * H];
__device__ unsigned short g_ah[(size_t)N_NODES * H];   // activation hi bf16
__device__ unsigned short g_al[(size_t)N_NODES * H];   // activation lo bf16
__device__ unsigned short g_wh[H * H];                 // weight^T hi bf16 [N][K]
__device__ unsigned short g_wl[H * H];                 // weight^T lo bf16
__device__ float          g_dinv[N_NODES];
__device__ int            g_degi[N_NODES];
__device__ int            g_cursor[N_NODES];
__device__ int            g_rowptr[N_NODES + 1];
__device__ int            g_csrsrc[N_EDGES];
__device__ float          g_aS[(size_t)N_NODES * NH];
__device__ float          g_aD[(size_t)N_NODES * NH];
__device__ float          g_pool[NG * H];
__device__ float          g_zb[NG * H2];

__device__ inline int clampi(int v, int hi) { return (v < 0) ? 0 : (v >= hi ? hi - 1 : v); }

__device__ inline unsigned short bf16rn(float f) {
    unsigned u = __float_as_uint(f);
    unsigned r = u + 0x7fffu + ((u >> 16) & 1u);   // RNE; inputs finite
    return (unsigned short)(r >> 16);
}
__device__ inline float bf16f(unsigned short h) { return __uint_as_float((unsigned)h << 16); }

// async global->LDS, 16B per lane: lane i writes lds_base + i*16 (wave-uniform base)
__device__ inline void gload_lds16(const unsigned short* g, unsigned short* s) {
    __builtin_amdgcn_global_load_lds(
        (const __attribute__((address_space(1))) void*)g,
        (__attribute__((address_space(3))) void*)s, 16, 0, 0);
}

// ---------------- CSR build ----------------
__global__ void fill_i32(int* p, int n, int v) {
    int i = blockIdx.x * blockDim.x + threadIdx.x;
    if (i < n) p[i] = v;
}

__global__ void count_deg(const int* __restrict__ dst, int* __restrict__ degi) {
    int e = blockIdx.x * blockDim.x + threadIdx.x;
    if (e < N_EDGES) atomicAdd(&degi[clampi(dst[e], N_NODES)], 1);
}

__global__ void dinv_k(const int* __restrict__ degi, float* __restrict__ dinv) {
    int i = blockIdx.x * blockDim.x + threadIdx.x;
    if (i < N_NODES) dinv[i] = rsqrtf((float)degi[i] + 1.0f);   // +1 = self-loop
}

__global__ __launch_bounds__(1024) void scan_rowptr(const int* __restrict__ degi,
                                                    int* __restrict__ rowptr,
                                                    int* __restrict__ cursor) {
    __shared__ int buf[1024];
    __shared__ int carry;
    int tid = threadIdx.x;
    if (tid == 0) carry = 0;
    __syncthreads();
    for (int base = 0; base < N_NODES; base += 1024) {
        int idx = base + tid;
        int v = (idx < N_NODES) ? degi[idx] : 0;
        buf[tid] = v;
        __syncthreads();
        for (int off = 1; off < 1024; off <<= 1) {
            int t = (tid >= off) ? buf[tid - off] : 0;
            __syncthreads();
            buf[tid] += t;
            __syncthreads();
        }
        if (idx < N_NODES) {
            int excl = buf[tid] - v + carry;
            rowptr[idx] = excl;
            cursor[idx] = excl;
        }
        int total = buf[1023];
        __syncthreads();
        if (tid == 0) carry += total;
        __syncthreads();
    }
    if (tid == 0) rowptr[N_NODES] = carry;
}

__global__ void bin_edges(const int* __restrict__ src, const int* __restrict__ dst,
                          int* __restrict__ cursor, int* __restrict__ csrsrc) {
    int e = blockIdx.x * blockDim.x + threadIdx.x;
    if (e >= N_EDGES) return;
    int d = clampi(dst[e], N_NODES);
    int pos = atomicAdd(&cursor[d], 1);
    if (pos >= 0 && pos < N_EDGES) csrsrc[pos] = clampi(src[e], N_NODES);
}

// ---------------- GEMM: x@w1 (K=3) ----------------
__global__ void gemm_k3(const float* __restrict__ x, const float* __restrict__ w,
                        float* __restrict__ out) {
    int idx = blockIdx.x * blockDim.x + threadIdx.x;
    if (idx >= N_NODES * H) return;
    int n = idx / H, j = idx % H;
    float x0 = x[n*3], x1 = x[n*3+1], x2 = x[n*3+2];
    out[idx] = x0 * w[j] + x1 * w[H + j] + x2 * w[2*H + j];
}

// weights: w[K][N] fp32 -> transposed hi/lo bf16 [N][K]
__global__ void split_wT(const float* __restrict__ w, unsigned short* __restrict__ hi,
                         unsigned short* __restrict__ lo) {
    int idx = blockIdx.x * blockDim.x + threadIdx.x;   // over H*H
    if (idx >= H * H) return;
    int n = idx % H, k = idx / H;                      // read coalesced in n
    float v = w[(size_t)k * H + n];
    unsigned short h = bf16rn(v);
    hi[(size_t)n * H + k] = h;
    lo[(size_t)n * H + k] = bf16rn(v - bf16f(h));
}

// ---------------- bf16x3 MFMA GEMM (round-6 proven K-loop) ----------------
// C[M,768] = A[M,768] @ W; A,W pre-split bf16 hi/lo; W transposed [N][K].
// 128x128 tile, 256 threads (4 waves), wave = 64x64 via 4x4 of 16x16x32 MFMA.
// All four operand arrays staged via wave-specialized global_load_lds width=16,
// single-buffered 32 KB (stage -> barrier -> MFMA -> barrier). History:
//   r6  single-buffer, all-LDS:            286 us  <- best, reverted to this
//   r7  dbuf 64 KB:                        290 us  (occupancy 30->20% ate the gain)
//   r8  B direct-from-global + A dbuf:     382 us  (B-load vmcnt(0) drained the
//       async prefetch every iter -- global_load & global_load_lds share vmcnt)
// If asf/adf nonnull (GAT layers), epilogue also emits alpha_src/alpha_dst:
// each wave's 64 cols = one full head; per-lane 4-col dot + 16-lane shfl_xor
// reduce gives final aS/aD (verified r8: absmax unchanged).
__global__ __launch_bounds__(256) void gemm_bf16x3(const unsigned short* __restrict__ ah,
                                                   const unsigned short* __restrict__ al,
                                                   const unsigned short* __restrict__ bth,
                                                   const unsigned short* __restrict__ btl,
                                                   float* __restrict__ C, int M,
                                                   const float* __restrict__ asf,
                                                   const float* __restrict__ adf,
                                                   float* __restrict__ aS,
                                                   float* __restrict__ aD) {
    __shared__ unsigned short sAh[128 * 32], sAl[128 * 32];
    __shared__ unsigned short sBh[128 * 32], sBl[128 * 32];
    int tid = threadIdx.x;
    int wave = tid >> 6, lane = tid & 63;
    int quad = lane >> 4, l16 = lane & 15;

    int id = blockIdx.x;
    int x = id & 7;            // XCD slot (round-robin); strips grouped per-XCD
    int s = id >> 3;
    int strip = x + 8 * (s / 6);
    int colt = s % 6;
    if (strip >= (N_NODES + 127) / 128) return;
    int row0 = strip * 128, col0 = colt * 128;
    int wr = (wave >> 1) * 64, wc = (wave & 1) * 64;

    // wave-specialized staging: wave w stages one of Ah/Al/Bh/Bl (8 segs each)
    const unsigned short* gsrc;
    unsigned short* sdst;
    int gbase;
    if (wave == 0)      { gsrc = ah;  sdst = sAh; gbase = row0; }
    else if (wave == 1) { gsrc = al;  sdst = sAl; gbase = row0; }
    else if (wave == 2) { gsrc = bth; sdst = sBh; gbase = col0; }
    else                { gsrc = btl; sdst = sBl; gbase = col0; }
    int isA = (wave < 2);
    int rr = lane >> 2, kc = (lane & 3) << 3;   // 4 lanes per row, 8-ushort chunks

    const unsigned short* gptr[8];
    #pragma unroll
    for (int seg = 0; seg < 8; seg++) {
        int r = gbase + seg * 16 + rr;
        if (isA && r >= M) r = M - 1;   // clamped rows feed unstored C rows
        gptr[seg] = gsrc + (size_t)r * H + kc;
    }

    ffrag acc[4][4];
    #pragma unroll
    for (int i = 0; i < 4; i++)
        #pragma unroll
        for (int j = 0; j < 4; j++) { ffrag z = {0.f, 0.f, 0.f, 0.f}; acc[i][j] = z; }

    #pragma unroll 1
    for (int kt = 0; kt < H / 32; kt++) {
        int koff = kt * 32;
        #pragma unroll
        for (int seg = 0; seg < 8; seg++)
            gload_lds16(gptr[seg] + koff, sdst + seg * 512);
        __syncthreads();

        bfrag fah[4], fal[4], fbh[4], fbl[4];
        #pragma unroll
        for (int i = 0; i < 4; i++) {
            int r = wr + i * 16 + l16;
            fah[i] = *reinterpret_cast<const bfrag*>(&sAh[r * 32 + quad * 8]);
            fal[i] = *reinterpret_cast<const bfrag*>(&sAl[r * 32 + quad * 8]);
        }
        #pragma unroll
        for (int j = 0; j < 4; j++) {
            int c = wc + j * 16 + l16;
            fbh[j] = *reinterpret_cast<const bfrag*>(&sBh[c * 32 + quad * 8]);
            fbl[j] = *reinterpret_cast<const bfrag*>(&sBl[c * 32 + quad * 8]);
        }
        #pragma unroll
        for (int i = 0; i < 4; i++)
            #pragma unroll
            for (int j = 0; j < 4; j++) {
                acc[i][j] = __builtin_amdgcn_mfma_f32_16x16x32_bf16(fah[i], fbh[j], acc[i][j], 0, 0, 0);
                acc[i][j] = __builtin_amdgcn_mfma_f32_16x16x32_bf16(fah[i], fbl[j], acc[i][j], 0, 0, 0);
                acc[i][j] = __builtin_amdgcn_mfma_f32_16x16x32_bf16(fal[i], fbh[j], acc[i][j], 0, 0, 0);
            }
        __syncthreads();
    }

    // epilogue: C/D layout col=lane&15, row=quad*4+reg (m89-verified)
    #pragma unroll
    for (int i = 0; i < 4; i++)
        #pragma unroll
        for (int r = 0; r < 4; r++) {
            int row = row0 + wr + i * 16 + quad * 4 + r;
            if (row >= M) continue;
            #pragma unroll
            for (int j = 0; j < 4; j++)
                C[(size_t)row * H + col0 + wc + j * 16 + l16] = acc[i][j][r];
        }

    // fused GAT alpha: this wave covers one full head (64 cols) for 64 rows
    if (asf) {
        int head = (col0 + wc) >> 6;
        float as_c[4], ad_c[4];
        #pragma unroll
        for (int j = 0; j < 4; j++) {
            int col = col0 + wc + j * 16 + l16;
            as_c[j] = asf[col];
            ad_c[j] = adf[col];
        }
        #pragma unroll
        for (int i = 0; i < 4; i++)
            #pragma unroll
            for (int r = 0; r < 4; r++) {
                float ps = 0.f, pd = 0.f;
                #pragma unroll
                for (int j = 0; j < 4; j++) {
                    ps += acc[i][j][r] * as_c[j];
                    pd += acc[i][j][r] * ad_c[j];
                }
                ps += __shfl_xor(ps, 1);  pd += __shfl_xor(pd, 1);
                ps += __shfl_xor(ps, 2);  pd += __shfl_xor(pd, 2);
                ps += __shfl_xor(ps, 4);  pd += __shfl_xor(pd, 4);
                ps += __shfl_xor(ps, 8);  pd += __shfl_xor(pd, 8);
                int row = row0 + wr + i * 16 + quad * 4 + r;
                if (l16 == 0 && row < M) {
                    aS[row * NH + head] = ps;
                    aD[row * NH + head] = pd;
                }
            }
    }
}

// ---------------- fused GCN gather (self + edges + bias + relu + bf16 split) ----
__global__ void gcn_gather(const int* __restrict__ rowptr, const int* __restrict__ csrsrc,
                           const float* __restrict__ h, const float* __restrict__ dinv,
                           const float* __restrict__ bias,
                           unsigned short* __restrict__ hi, unsigned short* __restrict__ lo) {
    int d = blockIdx.x;
    int t = threadIdx.x;
    float dd = dinv[d];
    float4 v = ((const float4*)(h + (size_t)d * H))[t];
    float c = dd * dd;
    float4 acc; acc.x = v.x * c; acc.y = v.y * c; acc.z = v.z * c; acc.w = v.w * c;
    int beg = rowptr[d], end = rowptr[d + 1];
    for (int i = beg; i < end; i++) {
        int s = csrsrc[i];
        float cc = dinv[s] * dd;
        float4 u = ((const float4*)(h + (size_t)s * H))[t];
        acc.x += u.x * cc; acc.y += u.y * cc; acc.z += u.z * cc; acc.w += u.w * cc;
    }
    float4 b = ((const float4*)bias)[t];
    acc.x = fmaxf(acc.x + b.x, 0.f); acc.y = fmaxf(acc.y + b.y, 0.f);
    acc.z = fmaxf(acc.z + b.z, 0.f); acc.w = fmaxf(acc.w + b.w, 0.f);
    ushort4 h4, l4;
    h4.x = bf16rn(acc.x); l4.x = bf16rn(acc.x - bf16f(h4.x));
    h4.y = bf16rn(acc.y); l4.y = bf16rn(acc.y - bf16f(h4.y));
    h4.z = bf16rn(acc.z); l4.z = bf16rn(acc.z - bf16f(h4.z));
    h4.w = bf16rn(acc.w); l4.w = bf16rn(acc.w - bf16f(h4.w));
    ((ushort4*)(hi + (size_t)d * H))[t] = h4;
    ((ushort4*)(lo + (size_t)d * H))[t] = l4;
}

__device__ inline float lrelu(float v) { return (v > 0.f) ? v : 0.2f * v; }

// fused softmax + weighted aggregation + bias (+relu); one block per dst node.
__global__ void gat_gather(const int* __restrict__ rowptr, const int* __restrict__ csrsrc,
                           const float* __restrict__ h, const float* __restrict__ aS,
                           const float* __restrict__ aD, const float* __restrict__ bias,
                           float* __restrict__ out,
                           unsigned short* __restrict__ hi, unsigned short* __restrict__ lo,
                           int relu) {
    int d = blockIdx.x;
    int t = threadIdx.x;
    int hh = t >> 4;
    int beg = rowptr[d], end = rowptr[d + 1];
    float adv = aD[d * NH + hh];
    float eself = lrelu(aS[d * NH + hh] + adv);
    float m = eself;
    for (int i = beg; i < end; i++)
        m = fmaxf(m, lrelu(aS[csrsrc[i] * NH + hh] + adv));
    float ssum = __expf(eself - m);
    for (int i = beg; i < end; i++)
        ssum += __expf(lrelu(aS[csrsrc[i] * NH + hh] + adv) - m);
    float inv = 1.0f / ssum;
    float cself = __expf(eself - m) * inv;
    float4 v = ((const float4*)(h + (size_t)d * H))[t];
    float4 acc; acc.x = v.x * cself; acc.y = v.y * cself; acc.z = v.z * cself; acc.w = v.w * cself;
    for (int i = beg; i < end; i++) {
        int s = csrsrc[i];
        float c = __expf(lrelu(aS[s * NH + hh] + adv) - m) * inv;
        float4 u = ((const float4*)(h + (size_t)s * H))[t];
        acc.x += u.x * c; acc.y += u.y * c; acc.z += u.z * c; acc.w += u.w * c;
    }
    float4 b = ((const float4*)bias)[t];
    acc.x += b.x; acc.y += b.y; acc.z += b.z; acc.w += b.w;
    if (relu) {
        acc.x = fmaxf(acc.x, 0.f); acc.y = fmaxf(acc.y, 0.f);
        acc.z = fmaxf(acc.z, 0.f); acc.w = fmaxf(acc.w, 0.f);
    }
    if (hi) {
        ushort4 h4, l4;
        h4.x = bf16rn(acc.x); l4.x = bf16rn(acc.x - bf16f(h4.x));
        h4.y = bf16rn(acc.y); l4.y = bf16rn(acc.y - bf16f(h4.y));
        h4.z = bf16rn(acc.z); l4.z = bf16rn(acc.z - bf16f(h4.z));
        h4.w = bf16rn(acc.w); l4.w = bf16rn(acc.w - bf16f(h4.w));
        ((ushort4*)(hi + (size_t)d * H))[t] = h4;
        ((ushort4*)(lo + (size_t)d * H))[t] = l4;
    } else {
        ((float4*)(out + (size_t)d * H))[t] = acc;
    }
}

// ---------------- pooling (batch is sorted) + classifier ----------------
__device__ inline int lower_bound_i(const int* b, int n, int key) {
    int lo = 0, hi = n;
    while (lo < hi) { int mid = (lo + hi) >> 1; if (b[mid] < key) lo = mid + 1; else hi = mid; }
    return lo;
}

__global__ void pool_graph(const int* __restrict__ batch, const float* __restrict__ h,
                           float* __restrict__ pool) {
    int g = blockIdx.x;   // NG blocks, 192 threads
    int t = threadIdx.x;
    int lo = lower_bound_i(batch, N_NODES, g);
    int hi = lower_bound_i(batch, N_NODES, g + 1);
    float4 a0 = {0,0,0,0}, a1 = {0,0,0,0}, a2 = {0,0,0,0}, a3 = {0,0,0,0};
    int n = lo;
    for (; n + 3 < hi; n += 4) {
        float4 v0 = ((const float4*)(h + (size_t)(n+0) * H))[t];
        float4 v1 = ((const float4*)(h + (size_t)(n+1) * H))[t];
        float4 v2 = ((const float4*)(h + (size_t)(n+2) * H))[t];
        float4 v3 = ((const float4*)(h + (size_t)(n+3) * H))[t];
        a0.x += v0.x; a0.y += v0.y; a0.z += v0.z; a0.w += v0.w;
        a1.x += v1.x; a1.y += v1.y; a1.z += v1.z; a1.w += v1.w;
        a2.x += v2.x; a2.y += v2.y; a2.z += v2.z; a2.w += v2.w;
        a3.x += v3.x; a3.y += v3.y; a3.z += v3.z; a3.w += v3.w;
    }
    for (; n < hi; n++) {
        float4 v = ((const float4*)(h + (size_t)n * H))[t];
        a0.x += v.x; a0.y += v.y; a0.z += v.z; a0.w += v.w;
    }
    float inv = 1.0f / fmaxf((float)(hi - lo), 1.0f);
    float4 o;
    o.x = (a0.x + a1.x + a2.x + a3.x) * inv;
    o.y = (a0.y + a1.y + a2.y + a3.y) * inv;
    o.z = (a0.z + a1.z + a2.z + a3.z) * inv;
    o.w = (a0.w + a1.w + a2.w + a3.w) * inv;
    ((float4*)(pool + (size_t)g * H))[t] = o;
}

__global__ void mlp1(const float* __restrict__ g, const float* __restrict__ w,
                     const float* __restrict__ b, float* __restrict__ z) {
    int idx = blockIdx.x * blockDim.x + threadIdx.x;
    if (idx >= NG * H2) return;
    int gg = idx / H2, j = idx % H2;
    const float* gp = g + (size_t)gg * H;
    float acc = b[j];
    for (int k = 0; k < H; k++) acc += gp[k] * w[(size_t)k * H2 + j];
    z[idx] = fmaxf(acc, 0.f);
}

__global__ void mlp2(const float* __restrict__ z, const float* __restrict__ w,
                     const float* __restrict__ b, float* __restrict__ out) {
    int idx = blockIdx.x * blockDim.x + threadIdx.x;
    if (idx >= NG * NC) return;
    int gg = idx / NC, c = idx % NC;
    const float* zp = z + (size_t)gg * H2;
    float acc = b[c];
    for (int k = 0; k < H2; k++) acc += zp[k] * w[(size_t)k * NC + c];
    out[idx] = acc;
}

// ---------------- launch ----------------
extern "C" void kernel_launch(void* const* d_in, const int* in_sizes, int n_in,
                              void* d_out, int out_size, void* d_ws, size_t ws_size,
                              hipStream_t stream) {
    (void)d_ws; (void)ws_size;
    const float* x     = (const float*)d_in[0];
    const int*   ei    = (const int*)d_in[1];
    const int*   batch = (const int*)d_in[2];
    const float* w1  = (const float*)d_in[3];  const float* b1  = (const float*)d_in[4];
    const float* w2  = (const float*)d_in[5];  const float* b2  = (const float*)d_in[6];
    const float* w3  = (const float*)d_in[7];  const float* b3  = (const float*)d_in[8];
    const float* wg1 = (const float*)d_in[9];  const float* as1 = (const float*)d_in[10];
    const float* ad1 = (const float*)d_in[11]; const float* bg1 = (const float*)d_in[12];
    const float* wg2 = (const float*)d_in[13]; const float* as2 = (const float*)d_in[14];
    const float* ad2 = (const float*)d_in[15]; const float* bg2 = (const float*)d_in[16];
    const float* wc1 = (const float*)d_in[17]; const float* bc1 = (const float*)d_in[18];
    const float* wc2 = (const float*)d_in[19]; const float* bc2 = (const float*)d_in[20];

    const int* srcp = ei;            // edge_index[0]
    const int* dstp = ei + N_EDGES;  // edge_index[1]

    float *bufA, *bufB, *dinv, *aS, *aD, *pool, *zb;
    unsigned short *ah, *al, *wh, *wl;
    int *degi, *cursor, *rowptr, *csrsrc;
    hipGetSymbolAddress((void**)&bufA,   HIP_SYMBOL(g_bufA));
    hipGetSymbolAddress((void**)&bufB,   HIP_SYMBOL(g_bufB));
    hipGetSymbolAddress((void**)&ah,     HIP_SYMBOL(g_ah));
    hipGetSymbolAddress((void**)&al,     HIP_SYMBOL(g_al));
    hipGetSymbolAddress((void**)&wh,     HIP_SYMBOL(g_wh));
    hipGetSymbolAddress((void**)&wl,     HIP_SYMBOL(g_wl));
    hipGetSymbolAddress((void**)&dinv,   HIP_SYMBOL(g_dinv));
    hipGetSymbolAddress((void**)&degi,   HIP_SYMBOL(g_degi));
    hipGetSymbolAddress((void**)&cursor, HIP_SYMBOL(g_cursor));
    hipGetSymbolAddress((void**)&rowptr, HIP_SYMBOL(g_rowptr));
    hipGetSymbolAddress((void**)&csrsrc, HIP_SYMBOL(g_csrsrc));
    hipGetSymbolAddress((void**)&aS,     HIP_SYMBOL(g_aS));
    hipGetSymbolAddress((void**)&aD,     HIP_SYMBOL(g_aD));
    hipGetSymbolAddress((void**)&pool,   HIP_SYMBOL(g_pool));
    hipGetSymbolAddress((void**)&zb,     HIP_SYMBOL(g_zb));

    auto cdiv = [](int a, int b) { return (a + b - 1) / b; };
    // strips padded to 8-aligned (392) x 6 col tiles; kernel guards spill
    int ggrid = 8 * cdiv(cdiv(N_NODES, 128), 8) * (H / 128);   // 2352

    // ---- CSR build (per call; inputs re-restored each launch) ----
    fill_i32<<<cdiv(N_NODES,256),256,0,stream>>>(degi, N_NODES, 0);
    count_deg<<<cdiv(N_EDGES,256),256,0,stream>>>(dstp, degi);
    dinv_k<<<cdiv(N_NODES,256),256,0,stream>>>(degi, dinv);
    scan_rowptr<<<1,1024,0,stream>>>(degi, rowptr, cursor);
    bin_edges<<<cdiv(N_EDGES,256),256,0,stream>>>(srcp, dstp, cursor, csrsrc);

    // ---- GCN1 (K=3 GEMM stays fp32 vector) ----
    gemm_k3<<<cdiv(N_NODES*H,256),256,0,stream>>>(x, w1, bufA);
    gcn_gather<<<N_NODES,192,0,stream>>>(rowptr, csrsrc, bufA, dinv, b1, ah, al);

    // ---- GCN2 ----
    split_wT<<<cdiv(H*H,256),256,0,stream>>>(w2, wh, wl);
    gemm_bf16x3<<<ggrid,256,0,stream>>>(ah, al, wh, wl, bufA, N_NODES,
                                        (const float*)nullptr, (const float*)nullptr,
                                        (float*)nullptr, (float*)nullptr);
    gcn_gather<<<N_NODES,192,0,stream>>>(rowptr, csrsrc, bufA, dinv, b2, ah, al);

    // ---- GCN3 ----
    split_wT<<<cdiv(H*H,256),256,0,stream>>>(w3, wh, wl);
    gemm_bf16x3<<<ggrid,256,0,stream>>>(ah, al, wh, wl, bufA, N_NODES,
                                        (const float*)nullptr, (const float*)nullptr,
                                        (float*)nullptr, (float*)nullptr);
    gcn_gather<<<N_NODES,192,0,stream>>>(rowptr, csrsrc, bufA, dinv, b3, ah, al);

    // ---- GAT1 (alpha fused into GEMM epilogue) ----
    split_wT<<<cdiv(H*H,256),256,0,stream>>>(wg1, wh, wl);
    gemm_bf16x3<<<ggrid,256,0,stream>>>(ah, al, wh, wl, bufA, N_NODES,
                                        as1, ad1, aS, aD);
    gat_gather<<<N_NODES,192,0,stream>>>(rowptr, csrsrc, bufA, aS, aD, bg1,
                                         (float*)nullptr, ah, al, 1);

    // ---- GAT2 (no relu; fp32 out for pooling) ----
    split_wT<<<cdiv(H*H,256),256,0,stream>>>(wg2, wh, wl);
    gemm_bf16x3<<<ggrid,256,0,stream>>>(ah, al, wh, wl, bufA, N_NODES,
                                        as2, ad2, aS, aD);
    gat_gather<<<N_NODES,192,0,stream>>>(rowptr, csrsrc, bufA, aS, aD, bg2,
                                         bufB, (unsigned short*)nullptr, (unsigned short*)nullptr, 0);

    // ---- pool + classifier ----
    pool_graph<<<NG,192,0,stream>>>(batch, bufB, pool);
    mlp1<<<cdiv(NG*H2,256),256,0,stream>>>(pool, wc1, bc1, zb);
    mlp2<<<cdiv(NG*NC,64),64,0,stream>>>(zb, wc2, bc2, (float*)d_out);
}

// Round 10
// 1436.496 us; speedup vs baseline: 1.7248x; 1.5234x over previous
//
#include <hip/hip_runtime.h>
#include <math.h>

#define N_NODES 50000
#define N_EDGES 100000
#define H 768
#define NH 12
#define HD 64
#define NG 64
#define NC 10
#define H2 384

typedef _Float16 h8  __attribute__((ext_vector_type(8)));   // 8 fp16 (4 VGPR)
typedef _Float16 h4v __attribute__((ext_vector_type(4)));
typedef float    ffrag __attribute__((ext_vector_type(4))); // MFMA acc

// ---------------- static device scratch ----------------
__device__ float    g_bufA[(size_t)N_NODES * H];
__device__ float    g_bufB[(size_t)N_NODES * H];
__device__ _Float16 g_ah[(size_t)N_NODES * H];   // activations fp16
__device__ _Float16 g_wh[H * H];                 // weight^T fp16 [N][K]
__device__ float    g_dinv[N_NODES];
__device__ int      g_degi[N_NODES];
__device__ int      g_cursor[N_NODES];
__device__ int      g_rowptr[N_NODES + 1];
__device__ int      g_csrsrc[N_EDGES];
__device__ float    g_aS[(size_t)N_NODES * NH];
__device__ float    g_aD[(size_t)N_NODES * NH];
__device__ float    g_pool[NG * H];
__device__ float    g_zb[NG * H2];

__device__ inline int clampi(int v, int hi) { return (v < 0) ? 0 : (v >= hi ? hi - 1 : v); }

// async global->LDS, 16B per lane: lane i writes lds_base + i*16 (wave-uniform base)
__device__ inline void gload_lds16(const _Float16* g, _Float16* s) {
    __builtin_amdgcn_global_load_lds(
        (const __attribute__((address_space(1))) void*)g,
        (__attribute__((address_space(3))) void*)s, 16, 0, 0);
}

// ---------------- CSR build ----------------
__global__ void fill_i32(int* p, int n, int v) {
    int i = blockIdx.x * blockDim.x + threadIdx.x;
    if (i < n) p[i] = v;
}

__global__ void count_deg(const int* __restrict__ dst, int* __restrict__ degi) {
    int e = blockIdx.x * blockDim.x + threadIdx.x;
    if (e < N_EDGES) atomicAdd(&degi[clampi(dst[e], N_NODES)], 1);
}

__global__ void dinv_k(const int* __restrict__ degi, float* __restrict__ dinv) {
    int i = blockIdx.x * blockDim.x + threadIdx.x;
    if (i < N_NODES) dinv[i] = rsqrtf((float)degi[i] + 1.0f);   // +1 = self-loop
}

__global__ __launch_bounds__(1024) void scan_rowptr(const int* __restrict__ degi,
                                                    int* __restrict__ rowptr,
                                                    int* __restrict__ cursor) {
    __shared__ int buf[1024];
    __shared__ int carry;
    int tid = threadIdx.x;
    if (tid == 0) carry = 0;
    __syncthreads();
    for (int base = 0; base < N_NODES; base += 1024) {
        int idx = base + tid;
        int v = (idx < N_NODES) ? degi[idx] : 0;
        buf[tid] = v;
        __syncthreads();
        for (int off = 1; off < 1024; off <<= 1) {
            int t = (tid >= off) ? buf[tid - off] : 0;
            __syncthreads();
            buf[tid] += t;
            __syncthreads();
        }
        if (idx < N_NODES) {
            int excl = buf[tid] - v + carry;
            rowptr[idx] = excl;
            cursor[idx] = excl;
        }
        int total = buf[1023];
        __syncthreads();
        if (tid == 0) carry += total;
        __syncthreads();
    }
    if (tid == 0) rowptr[N_NODES] = carry;
}

__global__ void bin_edges(const int* __restrict__ src, const int* __restrict__ dst,
                          int* __restrict__ cursor, int* __restrict__ csrsrc) {
    int e = blockIdx.x * blockDim.x + threadIdx.x;
    if (e >= N_EDGES) return;
    int d = clampi(dst[e], N_NODES);
    int pos = atomicAdd(&cursor[d], 1);
    if (pos >= 0 && pos < N_EDGES) csrsrc[pos] = clampi(src[e], N_NODES);
}

// ---------------- GEMM: x@w1 (K=3) ----------------
__global__ void gemm_k3(const float* __restrict__ x, const float* __restrict__ w,
                        float* __restrict__ out) {
    int idx = blockIdx.x * blockDim.x + threadIdx.x;
    if (idx >= N_NODES * H) return;
    int n = idx / H, j = idx % H;
    float x0 = x[n*3], x1 = x[n*3+1], x2 = x[n*3+2];
    out[idx] = x0 * w[j] + x1 * w[H + j] + x2 * w[2*H + j];
}

// weights: w[K][N] fp32 -> transposed fp16 [N][K]
__global__ void split_wT(const float* __restrict__ w, _Float16* __restrict__ hi) {
    int idx = blockIdx.x * blockDim.x + threadIdx.x;   // over H*H
    if (idx >= H * H) return;
    int n = idx % H, k = idx / H;                      // read coalesced in n
    hi[(size_t)n * H + k] = (_Float16)w[(size_t)k * H + n];
}

// ---------------- fp16 MFMA GEMM, double-buffered ----------------
// C[M,768] = A[M,768] @ W; A,W in fp16 (2^-11 rel error vs bf16's 2^-8); W^T [N][K].
// 128x128 tile, 256 threads (4 waves), wave = 64x64 via 4x4 of 16x16x32 MFMA.
// History: bf16x3 was LDS-pipe-bound (r9: 32KB staged + 64KB ds_read per
// block-iter >> MFMA 690cyc). fp16x1 halves every staged/read byte and cuts
// MFMA 3x. Double-buffer now fits in 32KB total (r7's dbuf failed only on
// occupancy at 64KB). Staging: wave w stages 4 of 16 segs via global_load_lds
// width=16. XCD swizzle: strip = (id&7)+8*((id>>3)/6) keeps a strip's 6
// col-tiles on one XCD (r6-verified: FETCH dropped 8x).
// asf/adf nonnull (GAT): epilogue emits alpha_src/dst per wave-head (r8-verified).
__global__ __launch_bounds__(256) void gemm_f16(const _Float16* __restrict__ a,
                                                const _Float16* __restrict__ bt,
                                                float* __restrict__ C, int M,
                                                const float* __restrict__ asf,
                                                const float* __restrict__ adf,
                                                float* __restrict__ aS,
                                                float* __restrict__ aD) {
    __shared__ _Float16 sA[2][128 * 32], sB[2][128 * 32];
    int tid = threadIdx.x;
    int wave = tid >> 6, lane = tid & 63;
    int quad = lane >> 4, l16 = lane & 15;

    int id = blockIdx.x;
    int x = id & 7;
    int s = id >> 3;
    int strip = x + 8 * (s / 6);
    int colt = s % 6;
    if (strip >= (N_NODES + 127) / 128) return;
    int row0 = strip * 128, col0 = colt * 128;
    int wr = (wave >> 1) * 64, wc = (wave & 1) * 64;

    // staging: waves 0,1 -> A segs 0-3 / 4-7; waves 2,3 -> B segs 0-3 / 4-7
    int isA = (wave < 2);
    const _Float16* gsrc = isA ? a : bt;
    int gbase = isA ? row0 : col0;
    int segbase = (wave & 1) * 4;
    int rr = lane >> 2, kc = (lane & 3) << 3;   // 4 lanes/row, 8-half chunks
    const _Float16* gptr[4];
    int soff[4];
    #pragma unroll
    for (int k = 0; k < 4; k++) {
        int seg = segbase + k;
        int r = gbase + seg * 16 + rr;
        if (isA && r >= M) r = M - 1;   // clamped rows feed unstored C rows
        gptr[k] = gsrc + (size_t)r * H + kc;
        soff[k] = seg * 512;
    }
    _Float16* sd0 = isA ? sA[0] : sB[0];
    _Float16* sd1 = isA ? sA[1] : sB[1];

    ffrag acc[4][4];
    #pragma unroll
    for (int i = 0; i < 4; i++)
        #pragma unroll
        for (int j = 0; j < 4; j++) { ffrag z = {0.f, 0.f, 0.f, 0.f}; acc[i][j] = z; }

    // prologue: stage k-tile 0 into buf 0
    #pragma unroll
    for (int k = 0; k < 4; k++)
        gload_lds16(gptr[k], sd0 + soff[k]);

    #pragma unroll 1
    for (int kt = 0; kt < H / 32; kt++) {
        int cur = kt & 1;
        __syncthreads();   // buf[cur] loads complete (compiler vmcnt drain)
        if (kt + 1 < H / 32) {
            _Float16* nb = cur ? sd0 : sd1;
            int koff = (kt + 1) * 32;
            #pragma unroll
            for (int k = 0; k < 4; k++)
                gload_lds16(gptr[k] + koff, nb + soff[k]);
        }

        const _Float16* pA = sA[cur];
        const _Float16* pB = sB[cur];
        h8 fa[4], fb[4];
        #pragma unroll
        for (int i = 0; i < 4; i++)
            fa[i] = *reinterpret_cast<const h8*>(&pA[(wr + i * 16 + l16) * 32 + quad * 8]);
        #pragma unroll
        for (int j = 0; j < 4; j++)
            fb[j] = *reinterpret_cast<const h8*>(&pB[(wc + j * 16 + l16) * 32 + quad * 8]);
        #pragma unroll
        for (int i = 0; i < 4; i++)
            #pragma unroll
            for (int j = 0; j < 4; j++)
                acc[i][j] = __builtin_amdgcn_mfma_f32_16x16x32_f16(fa[i], fb[j], acc[i][j], 0, 0, 0);
    }

    // epilogue: C/D layout col=lane&15, row=quad*4+reg (m89-verified)
    #pragma unroll
    for (int i = 0; i < 4; i++)
        #pragma unroll
        for (int r = 0; r < 4; r++) {
            int row = row0 + wr + i * 16 + quad * 4 + r;
            if (row >= M) continue;
            #pragma unroll
            for (int j = 0; j < 4; j++)
                C[(size_t)row * H + col0 + wc + j * 16 + l16] = acc[i][j][r];
        }

    // fused GAT alpha: this wave covers one full head (64 cols) for 64 rows
    if (asf) {
        int head = (col0 + wc) >> 6;
        float as_c[4], ad_c[4];
        #pragma unroll
        for (int j = 0; j < 4; j++) {
            int col = col0 + wc + j * 16 + l16;
            as_c[j] = asf[col];
            ad_c[j] = adf[col];
        }
        #pragma unroll
        for (int i = 0; i < 4; i++)
            #pragma unroll
            for (int r = 0; r < 4; r++) {
                float ps = 0.f, pd = 0.f;
                #pragma unroll
                for (int j = 0; j < 4; j++) {
                    ps += acc[i][j][r] * as_c[j];
                    pd += acc[i][j][r] * ad_c[j];
                }
                ps += __shfl_xor(ps, 1);  pd += __shfl_xor(pd, 1);
                ps += __shfl_xor(ps, 2);  pd += __shfl_xor(pd, 2);
                ps += __shfl_xor(ps, 4);  pd += __shfl_xor(pd, 4);
                ps += __shfl_xor(ps, 8);  pd += __shfl_xor(pd, 8);
                int row = row0 + wr + i * 16 + quad * 4 + r;
                if (l16 == 0 && row < M) {
                    aS[row * NH + head] = ps;
                    aD[row * NH + head] = pd;
                }
            }
    }
}

// ---------------- fused GCN gather (self + edges + bias + relu + fp16 cast) ----
__global__ void gcn_gather(const int* __restrict__ rowptr, const int* __restrict__ csrsrc,
                           const float* __restrict__ h, const float* __restrict__ dinv,
                           const float* __restrict__ bias, _Float16* __restrict__ hi) {
    int d = blockIdx.x;
    int t = threadIdx.x;
    float dd = dinv[d];
    float4 v = ((const float4*)(h + (size_t)d * H))[t];
    float c = dd * dd;
    float4 acc; acc.x = v.x * c; acc.y = v.y * c; acc.z = v.z * c; acc.w = v.w * c;
    int beg = rowptr[d], end = rowptr[d + 1];
    for (int i = beg; i < end; i++) {
        int s = csrsrc[i];
        float cc = dinv[s] * dd;
        float4 u = ((const float4*)(h + (size_t)s * H))[t];
        acc.x += u.x * cc; acc.y += u.y * cc; acc.z += u.z * cc; acc.w += u.w * cc;
    }
    float4 b = ((const float4*)bias)[t];
    h4v o;
    o[0] = (_Float16)fmaxf(acc.x + b.x, 0.f);
    o[1] = (_Float16)fmaxf(acc.y + b.y, 0.f);
    o[2] = (_Float16)fmaxf(acc.z + b.z, 0.f);
    o[3] = (_Float16)fmaxf(acc.w + b.w, 0.f);
    ((h4v*)(hi + (size_t)d * H))[t] = o;
}

__device__ inline float lrelu(float v) { return (v > 0.f) ? v : 0.2f * v; }

// fused softmax + weighted aggregation + bias (+relu); one block per dst node.
// hi nonnull -> write fp16 (next GEMM input); else fp32 to out (pooling).
__global__ void gat_gather(const int* __restrict__ rowptr, const int* __restrict__ csrsrc,
                           const float* __restrict__ h, const float* __restrict__ aS,
                           const float* __restrict__ aD, const float* __restrict__ bias,
                           float* __restrict__ out, _Float16* __restrict__ hi, int relu) {
    int d = blockIdx.x;
    int t = threadIdx.x;
    int hh = t >> 4;
    int beg = rowptr[d], end = rowptr[d + 1];
    float adv = aD[d * NH + hh];
    float eself = lrelu(aS[d * NH + hh] + adv);
    float m = eself;
    for (int i = beg; i < end; i++)
        m = fmaxf(m, lrelu(aS[csrsrc[i] * NH + hh] + adv));
    float ssum = __expf(eself - m);
    for (int i = beg; i < end; i++)
        ssum += __expf(lrelu(aS[csrsrc[i] * NH + hh] + adv) - m);
    float inv = 1.0f / ssum;
    float cself = __expf(eself - m) * inv;
    float4 v = ((const float4*)(h + (size_t)d * H))[t];
    float4 acc; acc.x = v.x * cself; acc.y = v.y * cself; acc.z = v.z * cself; acc.w = v.w * cself;
    for (int i = beg; i < end; i++) {
        int s = csrsrc[i];
        float c = __expf(lrelu(aS[s * NH + hh] + adv) - m) * inv;
        float4 u = ((const float4*)(h + (size_t)s * H))[t];
        acc.x += u.x * c; acc.y += u.y * c; acc.z += u.z * c; acc.w += u.w * c;
    }
    float4 b = ((const float4*)bias)[t];
    acc.x += b.x; acc.y += b.y; acc.z += b.z; acc.w += b.w;
    if (relu) {
        acc.x = fmaxf(acc.x, 0.f); acc.y = fmaxf(acc.y, 0.f);
        acc.z = fmaxf(acc.z, 0.f); acc.w = fmaxf(acc.w, 0.f);
    }
    if (hi) {
        h4v o;
        o[0] = (_Float16)acc.x; o[1] = (_Float16)acc.y;
        o[2] = (_Float16)acc.z; o[3] = (_Float16)acc.w;
        ((h4v*)(hi + (size_t)d * H))[t] = o;
    } else {
        ((float4*)(out + (size_t)d * H))[t] = acc;
    }
}

// ---------------- pooling (batch is sorted) + classifier ----------------
__device__ inline int lower_bound_i(const int* b, int n, int key) {
    int lo = 0, hi = n;
    while (lo < hi) { int mid = (lo + hi) >> 1; if (b[mid] < key) lo = mid + 1; else hi = mid; }
    return lo;
}

__global__ void pool_graph(const int* __restrict__ batch, const float* __restrict__ h,
                           float* __restrict__ pool) {
    int g = blockIdx.x;   // NG blocks, 192 threads
    int t = threadIdx.x;
    int lo = lower_bound_i(batch, N_NODES, g);
    int hi = lower_bound_i(batch, N_NODES, g + 1);
    float4 a0 = {0,0,0,0}, a1 = {0,0,0,0}, a2 = {0,0,0,0}, a3 = {0,0,0,0};
    int n = lo;
    for (; n + 3 < hi; n += 4) {
        float4 v0 = ((const float4*)(h + (size_t)(n+0) * H))[t];
        float4 v1 = ((const float4*)(h + (size_t)(n+1) * H))[t];
        float4 v2 = ((const float4*)(h + (size_t)(n+2) * H))[t];
        float4 v3 = ((const float4*)(h + (size_t)(n+3) * H))[t];
        a0.x += v0.x; a0.y += v0.y; a0.z += v0.z; a0.w += v0.w;
        a1.x += v1.x; a1.y += v1.y; a1.z += v1.z; a1.w += v1.w;
        a2.x += v2.x; a2.y += v2.y; a2.z += v2.z; a2.w += v2.w;
        a3.x += v3.x; a3.y += v3.y; a3.z += v3.z; a3.w += v3.w;
    }
    for (; n < hi; n++) {
        float4 v = ((const float4*)(h + (size_t)n * H))[t];
        a0.x += v.x; a0.y += v.y; a0.z += v.z; a0.w += v.w;
    }
    float inv = 1.0f / fmaxf((float)(hi - lo), 1.0f);
    float4 o;
    o.x = (a0.x + a1.x + a2.x + a3.x) * inv;
    o.y = (a0.y + a1.y + a2.y + a3.y) * inv;
    o.z = (a0.z + a1.z + a2.z + a3.z) * inv;
    o.w = (a0.w + a1.w + a2.w + a3.w) * inv;
    ((float4*)(pool + (size_t)g * H))[t] = o;
}

__global__ void mlp1(const float* __restrict__ g, const float* __restrict__ w,
                     const float* __restrict__ b, float* __restrict__ z) {
    int idx = blockIdx.x * blockDim.x + threadIdx.x;
    if (idx >= NG * H2) return;
    int gg = idx / H2, j = idx % H2;
    const float* gp = g + (size_t)gg * H;
    float acc = b[j];
    for (int k = 0; k < H; k++) acc += gp[k] * w[(size_t)k * H2 + j];
    z[idx] = fmaxf(acc, 0.f);
}

__global__ void mlp2(const float* __restrict__ z, const float* __restrict__ w,
                     const float* __restrict__ b, float* __restrict__ out) {
    int idx = blockIdx.x * blockDim.x + threadIdx.x;
    if (idx >= NG * NC) return;
    int gg = idx / NC, c = idx % NC;
    const float* zp = z + (size_t)gg * H2;
    float acc = b[c];
    for (int k = 0; k < H2; k++) acc += zp[k] * w[(size_t)k * NC + c];
    out[idx] = acc;
}

// ---------------- launch ----------------
extern "C" void kernel_launch(void* const* d_in, const int* in_sizes, int n_in,
                              void* d_out, int out_size, void* d_ws, size_t ws_size,
                              hipStream_t stream) {
    (void)d_ws; (void)ws_size;
    const float* x     = (const float*)d_in[0];
    const int*   ei    = (const int*)d_in[1];
    const int*   batch = (const int*)d_in[2];
    const float* w1  = (const float*)d_in[3];  const float* b1  = (const float*)d_in[4];
    const float* w2  = (const float*)d_in[5];  const float* b2  = (const float*)d_in[6];
    const float* w3  = (const float*)d_in[7];  const float* b3  = (const float*)d_in[8];
    const float* wg1 = (const float*)d_in[9];  const float* as1 = (const float*)d_in[10];
    const float* ad1 = (const float*)d_in[11]; const float* bg1 = (const float*)d_in[12];
    const float* wg2 = (const float*)d_in[13]; const float* as2 = (const float*)d_in[14];
    const float* ad2 = (const float*)d_in[15]; const float* bg2 = (const float*)d_in[16];
    const float* wc1 = (const float*)d_in[17]; const float* bc1 = (const float*)d_in[18];
    const float* wc2 = (const float*)d_in[19]; const float* bc2 = (const float*)d_in[20];

    const int* srcp = ei;            // edge_index[0]
    const int* dstp = ei + N_EDGES;  // edge_index[1]

    float *bufA, *bufB, *dinv, *aS, *aD, *pool, *zb;
    _Float16 *ah, *wh;
    int *degi, *cursor, *rowptr, *csrsrc;
    hipGetSymbolAddress((void**)&bufA,   HIP_SYMBOL(g_bufA));
    hipGetSymbolAddress((void**)&bufB,   HIP_SYMBOL(g_bufB));
    hipGetSymbolAddress((void**)&ah,     HIP_SYMBOL(g_ah));
    hipGetSymbolAddress((void**)&wh,     HIP_SYMBOL(g_wh));
    hipGetSymbolAddress((void**)&dinv,   HIP_SYMBOL(g_dinv));
    hipGetSymbolAddress((void**)&degi,   HIP_SYMBOL(g_degi));
    hipGetSymbolAddress((void**)&cursor, HIP_SYMBOL(g_cursor));
    hipGetSymbolAddress((void**)&rowptr, HIP_SYMBOL(g_rowptr));
    hipGetSymbolAddress((void**)&csrsrc, HIP_SYMBOL(g_csrsrc));
    hipGetSymbolAddress((void**)&aS,     HIP_SYMBOL(g_aS));
    hipGetSymbolAddress((void**)&aD,     HIP_SYMBOL(g_aD));
    hipGetSymbolAddress((void**)&pool,   HIP_SYMBOL(g_pool));
    hipGetSymbolAddress((void**)&zb,     HIP_SYMBOL(g_zb));

    auto cdiv = [](int a, int b) { return (a + b - 1) / b; };
    // strips padded to 8-aligned (392) x 6 col tiles; kernel guards spill
    int ggrid = 8 * cdiv(cdiv(N_NODES, 128), 8) * (H / 128);   // 2352

    // ---- CSR build (per call; inputs re-restored each launch) ----
    fill_i32<<<cdiv(N_NODES,256),256,0,stream>>>(degi, N_NODES, 0);
    count_deg<<<cdiv(N_EDGES,256),256,0,stream>>>(dstp, degi);
    dinv_k<<<cdiv(N_NODES,256),256,0,stream>>>(degi, dinv);
    scan_rowptr<<<1,1024,0,stream>>>(degi, rowptr, cursor);
    bin_edges<<<cdiv(N_EDGES,256),256,0,stream>>>(srcp, dstp, cursor, csrsrc);

    // ---- GCN1 (K=3 GEMM stays fp32 vector) ----
    gemm_k3<<<cdiv(N_NODES*H,256),256,0,stream>>>(x, w1, bufA);
    gcn_gather<<<N_NODES,192,0,stream>>>(rowptr, csrsrc, bufA, dinv, b1, ah);

    // ---- GCN2 ----
    split_wT<<<cdiv(H*H,256),256,0,stream>>>(w2, wh);
    gemm_f16<<<ggrid,256,0,stream>>>(ah, wh, bufA, N_NODES,
                                     (const float*)nullptr, (const float*)nullptr,
                                     (float*)nullptr, (float*)nullptr);
    gcn_gather<<<N_NODES,192,0,stream>>>(rowptr, csrsrc, bufA, dinv, b2, ah);

    // ---- GCN3 ----
    split_wT<<<cdiv(H*H,256),256,0,stream>>>(w3, wh);
    gemm_f16<<<ggrid,256,0,stream>>>(ah, wh, bufA, N_NODES,
                                     (const float*)nullptr, (const float*)nullptr,
                                     (float*)nullptr, (float*)nullptr);
    gcn_gather<<<N_NODES,192,0,stream>>>(rowptr, csrsrc, bufA, dinv, b3, ah);

    // ---- GAT1 (alpha fused into GEMM epilogue) ----
    split_wT<<<cdiv(H*H,256),256,0,stream>>>(wg1, wh);
    gemm_f16<<<ggrid,256,0,stream>>>(ah, wh, bufA, N_NODES, as1, ad1, aS, aD);
    gat_gather<<<N_NODES,192,0,stream>>>(rowptr, csrsrc, bufA, aS, aD, bg1,
                                         (float*)nullptr, ah, 1);

    // ---- GAT2 (no relu; fp32 out for pooling) ----
    split_wT<<<cdiv(H*H,256),256,0,stream>>>(wg2, wh);
    gemm_f16<<<ggrid,256,0,stream>>>(ah, wh, bufA, N_NODES, as2, ad2, aS, aD);
    gat_gather<<<N_NODES,192,0,stream>>>(rowptr, csrsrc, bufA, aS, aD, bg2,
                                         bufB, (_Float16*)nullptr, 0);

    // ---- pool + classifier ----
    pool_graph<<<NG,192,0,stream>>>(batch, bufB, pool);
    mlp1<<<cdiv(NG*H2,256),256,0,stream>>>(pool, wc1, bc1, zb);
    mlp2<<<cdiv(NG*NC,64),64,0,stream>>>(zb, wc2, bc2, (float*)d_out);
}

// Round 11
// 1317.912 us; speedup vs baseline: 1.8800x; 1.0900x over previous
//
#include <hip/hip_runtime.h>
#include <math.h>

#define N_NODES 50000
#define N_EDGES 100000
#define H 768
#define NH 12
#define HD 64
#define NG 64
#define NC 10
#define H2 384

typedef _Float16 h8  __attribute__((ext_vector_type(8)));   // 8 fp16 (4 VGPR)
typedef _Float16 h4v __attribute__((ext_vector_type(4)));
typedef float    ffrag __attribute__((ext_vector_type(4))); // MFMA acc

// ---------------- static device scratch ----------------
__device__ float    g_bufB[(size_t)N_NODES * H];   // GAT2 fp32 out (pool input)
__device__ _Float16 g_ah[(size_t)N_NODES * H];     // GEMM input acts fp16
__device__ _Float16 g_ch[(size_t)N_NODES * H];     // GEMM output / gather input fp16
__device__ _Float16 g_wh[H * H];                   // weight^T fp16 [N][K]
__device__ float    g_dinv[N_NODES];
__device__ int      g_degi[N_NODES];
__device__ int      g_cursor[N_NODES];
__device__ int      g_rowptr[N_NODES + 1];
__device__ int      g_csrsrc[N_EDGES];
__device__ float    g_aS[(size_t)N_NODES * NH];
__device__ float    g_aD[(size_t)N_NODES * NH];
__device__ float    g_pool[NG * H];
__device__ float    g_zb[NG * H2];

__device__ inline int clampi(int v, int hi) { return (v < 0) ? 0 : (v >= hi ? hi - 1 : v); }

// async global->LDS, 16B per lane: lane i writes lds_base + i*16 (wave-uniform base)
__device__ inline void gload_lds16(const _Float16* g, _Float16* s) {
    __builtin_amdgcn_global_load_lds(
        (const __attribute__((address_space(1))) void*)g,
        (__attribute__((address_space(3))) void*)s, 16, 0, 0);
}

// ---------------- CSR build ----------------
__global__ void fill_i32(int* p, int n, int v) {
    int i = blockIdx.x * blockDim.x + threadIdx.x;
    if (i < n) p[i] = v;
}

__global__ void count_deg(const int* __restrict__ dst, int* __restrict__ degi) {
    int e = blockIdx.x * blockDim.x + threadIdx.x;
    if (e < N_EDGES) atomicAdd(&degi[clampi(dst[e], N_NODES)], 1);
}

__global__ void dinv_k(const int* __restrict__ degi, float* __restrict__ dinv) {
    int i = blockIdx.x * blockDim.x + threadIdx.x;
    if (i < N_NODES) dinv[i] = rsqrtf((float)degi[i] + 1.0f);   // +1 = self-loop
}

__global__ __launch_bounds__(1024) void scan_rowptr(const int* __restrict__ degi,
                                                    int* __restrict__ rowptr,
                                                    int* __restrict__ cursor) {
    __shared__ int buf[1024];
    __shared__ int carry;
    int tid = threadIdx.x;
    if (tid == 0) carry = 0;
    __syncthreads();
    for (int base = 0; base < N_NODES; base += 1024) {
        int idx = base + tid;
        int v = (idx < N_NODES) ? degi[idx] : 0;
        buf[tid] = v;
        __syncthreads();
        for (int off = 1; off < 1024; off <<= 1) {
            int t = (tid >= off) ? buf[tid - off] : 0;
            __syncthreads();
            buf[tid] += t;
            __syncthreads();
        }
        if (idx < N_NODES) {
            int excl = buf[tid] - v + carry;
            rowptr[idx] = excl;
            cursor[idx] = excl;
        }
        int total = buf[1023];
        __syncthreads();
        if (tid == 0) carry += total;
        __syncthreads();
    }
    if (tid == 0) rowptr[N_NODES] = carry;
}

__global__ void bin_edges(const int* __restrict__ src, const int* __restrict__ dst,
                          int* __restrict__ cursor, int* __restrict__ csrsrc) {
    int e = blockIdx.x * blockDim.x + threadIdx.x;
    if (e >= N_EDGES) return;
    int d = clampi(dst[e], N_NODES);
    int pos = atomicAdd(&cursor[d], 1);
    if (pos >= 0 && pos < N_EDGES) csrsrc[pos] = clampi(src[e], N_NODES);
}

// ---------------- GEMM: x@w1 (K=3), fp16 out ----------------
__global__ void gemm_k3(const float* __restrict__ x, const float* __restrict__ w,
                        _Float16* __restrict__ out) {
    int idx = blockIdx.x * blockDim.x + threadIdx.x;
    if (idx >= N_NODES * H) return;
    int n = idx / H, j = idx % H;
    float x0 = x[n*3], x1 = x[n*3+1], x2 = x[n*3+2];
    out[idx] = (_Float16)(x0 * w[j] + x1 * w[H + j] + x2 * w[2*H + j]);
}

// weights: w[K][N] fp32 -> transposed fp16 [N][K]
__global__ void split_wT(const float* __restrict__ w, _Float16* __restrict__ hi) {
    int idx = blockIdx.x * blockDim.x + threadIdx.x;   // over H*H
    if (idx >= H * H) return;
    int n = idx % H, k = idx / H;                      // read coalesced in n
    hi[(size_t)n * H + k] = (_Float16)w[(size_t)k * H + n];
}

// ---------------- fp16 MFMA GEMM, double-buffered, fp16 C ----------------
// C[M,768] = A[M,768] @ W; fp16 in/out, fp32 MFMA accumulation; W^T [N][K].
// 128x128 tile, 256 threads (4 waves), wave = 64x64 via 4x4 of 16x16x32 MFMA.
// r10: fp16x1 (vs bf16x3) halved LDS/HBM bytes, 3x less MFMA -> 308->137 us.
// r11: C stored fp16 (consumers cast to fp16 anyway) -> halves C-write traffic
// and every downstream gather's read traffic. XCD swizzle r6-verified; fused
// GAT-alpha epilogue r8-verified.
__global__ __launch_bounds__(256) void gemm_f16(const _Float16* __restrict__ a,
                                                const _Float16* __restrict__ bt,
                                                _Float16* __restrict__ C, int M,
                                                const float* __restrict__ asf,
                                                const float* __restrict__ adf,
                                                float* __restrict__ aS,
                                                float* __restrict__ aD) {
    __shared__ _Float16 sA[2][128 * 32], sB[2][128 * 32];
    int tid = threadIdx.x;
    int wave = tid >> 6, lane = tid & 63;
    int quad = lane >> 4, l16 = lane & 15;

    int id = blockIdx.x;
    int x = id & 7;
    int s = id >> 3;
    int strip = x + 8 * (s / 6);
    int colt = s % 6;
    if (strip >= (N_NODES + 127) / 128) return;
    int row0 = strip * 128, col0 = colt * 128;
    int wr = (wave >> 1) * 64, wc = (wave & 1) * 64;

    // staging: waves 0,1 -> A segs 0-3 / 4-7; waves 2,3 -> B segs 0-3 / 4-7
    int isA = (wave < 2);
    const _Float16* gsrc = isA ? a : bt;
    int gbase = isA ? row0 : col0;
    int segbase = (wave & 1) * 4;
    int rr = lane >> 2, kc = (lane & 3) << 3;   // 4 lanes/row, 8-half chunks
    const _Float16* gptr[4];
    int soff[4];
    #pragma unroll
    for (int k = 0; k < 4; k++) {
        int seg = segbase + k;
        int r = gbase + seg * 16 + rr;
        if (isA && r >= M) r = M - 1;   // clamped rows feed unstored C rows
        gptr[k] = gsrc + (size_t)r * H + kc;
        soff[k] = seg * 512;
    }
    _Float16* sd0 = isA ? sA[0] : sB[0];
    _Float16* sd1 = isA ? sA[1] : sB[1];

    ffrag acc[4][4];
    #pragma unroll
    for (int i = 0; i < 4; i++)
        #pragma unroll
        for (int j = 0; j < 4; j++) { ffrag z = {0.f, 0.f, 0.f, 0.f}; acc[i][j] = z; }

    // prologue: stage k-tile 0 into buf 0
    #pragma unroll
    for (int k = 0; k < 4; k++)
        gload_lds16(gptr[k], sd0 + soff[k]);

    #pragma unroll 1
    for (int kt = 0; kt < H / 32; kt++) {
        int cur = kt & 1;
        __syncthreads();   // buf[cur] loads complete (compiler vmcnt drain)
        if (kt + 1 < H / 32) {
            _Float16* nb = cur ? sd0 : sd1;
            int koff = (kt + 1) * 32;
            #pragma unroll
            for (int k = 0; k < 4; k++)
                gload_lds16(gptr[k] + koff, nb + soff[k]);
        }

        const _Float16* pA = sA[cur];
        const _Float16* pB = sB[cur];
        h8 fa[4], fb[4];
        #pragma unroll
        for (int i = 0; i < 4; i++)
            fa[i] = *reinterpret_cast<const h8*>(&pA[(wr + i * 16 + l16) * 32 + quad * 8]);
        #pragma unroll
        for (int j = 0; j < 4; j++)
            fb[j] = *reinterpret_cast<const h8*>(&pB[(wc + j * 16 + l16) * 32 + quad * 8]);
        #pragma unroll
        for (int i = 0; i < 4; i++)
            #pragma unroll
            for (int j = 0; j < 4; j++)
                acc[i][j] = __builtin_amdgcn_mfma_f32_16x16x32_f16(fa[i], fb[j], acc[i][j], 0, 0, 0);
    }

    // epilogue: C/D layout col=lane&15, row=quad*4+reg (m89-verified); fp16 store
    #pragma unroll
    for (int i = 0; i < 4; i++)
        #pragma unroll
        for (int r = 0; r < 4; r++) {
            int row = row0 + wr + i * 16 + quad * 4 + r;
            if (row >= M) continue;
            #pragma unroll
            for (int j = 0; j < 4; j++)
                C[(size_t)row * H + col0 + wc + j * 16 + l16] = (_Float16)acc[i][j][r];
        }

    // fused GAT alpha: this wave covers one full head (64 cols) for 64 rows
    if (asf) {
        int head = (col0 + wc) >> 6;
        float as_c[4], ad_c[4];
        #pragma unroll
        for (int j = 0; j < 4; j++) {
            int col = col0 + wc + j * 16 + l16;
            as_c[j] = asf[col];
            ad_c[j] = adf[col];
        }
        #pragma unroll
        for (int i = 0; i < 4; i++)
            #pragma unroll
            for (int r = 0; r < 4; r++) {
                float ps = 0.f, pd = 0.f;
                #pragma unroll
                for (int j = 0; j < 4; j++) {
                    ps += acc[i][j][r] * as_c[j];
                    pd += acc[i][j][r] * ad_c[j];
                }
                ps += __shfl_xor(ps, 1);  pd += __shfl_xor(pd, 1);
                ps += __shfl_xor(ps, 2);  pd += __shfl_xor(pd, 2);
                ps += __shfl_xor(ps, 4);  pd += __shfl_xor(pd, 4);
                ps += __shfl_xor(ps, 8);  pd += __shfl_xor(pd, 8);
                int row = row0 + wr + i * 16 + quad * 4 + r;
                if (l16 == 0 && row < M) {
                    aS[row * NH + head] = ps;
                    aD[row * NH + head] = pd;
                }
            }
    }
}

// ---------------- fused GCN gather: fp16 in, fp32 accum, fp16 out ----------------
__global__ void gcn_gather(const int* __restrict__ rowptr, const int* __restrict__ csrsrc,
                           const _Float16* __restrict__ h, const float* __restrict__ dinv,
                           const float* __restrict__ bias, _Float16* __restrict__ hi) {
    int d = blockIdx.x;
    int t = threadIdx.x;   // 0..191, 4 halves each
    float dd = dinv[d];
    h4v v = ((const h4v*)(h + (size_t)d * H))[t];
    float c = dd * dd;
    float ax = (float)v[0] * c, ay = (float)v[1] * c, az = (float)v[2] * c, aw = (float)v[3] * c;
    int beg = rowptr[d], end = rowptr[d + 1];
    for (int i = beg; i < end; i++) {
        int s = csrsrc[i];
        float cc = dinv[s] * dd;
        h4v u = ((const h4v*)(h + (size_t)s * H))[t];
        ax += (float)u[0] * cc; ay += (float)u[1] * cc;
        az += (float)u[2] * cc; aw += (float)u[3] * cc;
    }
    float4 b = ((const float4*)bias)[t];
    h4v o;
    o[0] = (_Float16)fmaxf(ax + b.x, 0.f);
    o[1] = (_Float16)fmaxf(ay + b.y, 0.f);
    o[2] = (_Float16)fmaxf(az + b.z, 0.f);
    o[3] = (_Float16)fmaxf(aw + b.w, 0.f);
    ((h4v*)(hi + (size_t)d * H))[t] = o;
}

__device__ inline float lrelu(float v) { return (v > 0.f) ? v : 0.2f * v; }

// fused softmax + weighted aggregation + bias (+relu); one block per dst node.
// hi nonnull -> write fp16 (next GEMM input); else fp32 to out (pooling).
__global__ void gat_gather(const int* __restrict__ rowptr, const int* __restrict__ csrsrc,
                           const _Float16* __restrict__ h, const float* __restrict__ aS,
                           const float* __restrict__ aD, const float* __restrict__ bias,
                           float* __restrict__ out, _Float16* __restrict__ hi, int relu) {
    int d = blockIdx.x;
    int t = threadIdx.x;
    int hh = t >> 4;
    int beg = rowptr[d], end = rowptr[d + 1];
    float adv = aD[d * NH + hh];
    float eself = lrelu(aS[d * NH + hh] + adv);
    float m = eself;
    for (int i = beg; i < end; i++)
        m = fmaxf(m, lrelu(aS[csrsrc[i] * NH + hh] + adv));
    float ssum = __expf(eself - m);
    for (int i = beg; i < end; i++)
        ssum += __expf(lrelu(aS[csrsrc[i] * NH + hh] + adv) - m);
    float inv = 1.0f / ssum;
    float cself = __expf(eself - m) * inv;
    h4v v = ((const h4v*)(h + (size_t)d * H))[t];
    float ax = (float)v[0] * cself, ay = (float)v[1] * cself;
    float az = (float)v[2] * cself, aw = (float)v[3] * cself;
    for (int i = beg; i < end; i++) {
        int s = csrsrc[i];
        float c = __expf(lrelu(aS[s * NH + hh] + adv) - m) * inv;
        h4v u = ((const h4v*)(h + (size_t)s * H))[t];
        ax += (float)u[0] * c; ay += (float)u[1] * c;
        az += (float)u[2] * c; aw += (float)u[3] * c;
    }
    float4 b = ((const float4*)bias)[t];
    ax += b.x; ay += b.y; az += b.z; aw += b.w;
    if (relu) {
        ax = fmaxf(ax, 0.f); ay = fmaxf(ay, 0.f);
        az = fmaxf(az, 0.f); aw = fmaxf(aw, 0.f);
    }
    if (hi) {
        h4v o;
        o[0] = (_Float16)ax; o[1] = (_Float16)ay;
        o[2] = (_Float16)az; o[3] = (_Float16)aw;
        ((h4v*)(hi + (size_t)d * H))[t] = o;
    } else {
        float4 o; o.x = ax; o.y = ay; o.z = az; o.w = aw;
        ((float4*)(out + (size_t)d * H))[t] = o;
    }
}

// ---------------- pooling (batch is sorted) + classifier ----------------
__device__ inline int lower_bound_i(const int* b, int n, int key) {
    int lo = 0, hi = n;
    while (lo < hi) { int mid = (lo + hi) >> 1; if (b[mid] < key) lo = mid + 1; else hi = mid; }
    return lo;
}

__global__ void pool_graph(const int* __restrict__ batch, const float* __restrict__ h,
                           float* __restrict__ pool) {
    int g = blockIdx.x;   // NG blocks, 192 threads
    int t = threadIdx.x;
    int lo = lower_bound_i(batch, N_NODES, g);
    int hi = lower_bound_i(batch, N_NODES, g + 1);
    float4 a0 = {0,0,0,0}, a1 = {0,0,0,0}, a2 = {0,0,0,0}, a3 = {0,0,0,0};
    int n = lo;
    for (; n + 3 < hi; n += 4) {
        float4 v0 = ((const float4*)(h + (size_t)(n+0) * H))[t];
        float4 v1 = ((const float4*)(h + (size_t)(n+1) * H))[t];
        float4 v2 = ((const float4*)(h + (size_t)(n+2) * H))[t];
        float4 v3 = ((const float4*)(h + (size_t)(n+3) * H))[t];
        a0.x += v0.x; a0.y += v0.y; a0.z += v0.z; a0.w += v0.w;
        a1.x += v1.x; a1.y += v1.y; a1.z += v1.z; a1.w += v1.w;
        a2.x += v2.x; a2.y += v2.y; a2.z += v2.z; a2.w += v2.w;
        a3.x += v3.x; a3.y += v3.y; a3.z += v3.z; a3.w += v3.w;
    }
    for (; n < hi; n++) {
        float4 v = ((const float4*)(h + (size_t)n * H))[t];
        a0.x += v.x; a0.y += v.y; a0.z += v.z; a0.w += v.w;
    }
    float inv = 1.0f / fmaxf((float)(hi - lo), 1.0f);
    float4 o;
    o.x = (a0.x + a1.x + a2.x + a3.x) * inv;
    o.y = (a0.y + a1.y + a2.y + a3.y) * inv;
    o.z = (a0.z + a1.z + a2.z + a3.z) * inv;
    o.w = (a0.w + a1.w + a2.w + a3.w) * inv;
    ((float4*)(pool + (size_t)g * H))[t] = o;
}

__global__ void mlp1(const float* __restrict__ g, const float* __restrict__ w,
                     const float* __restrict__ b, float* __restrict__ z) {
    int idx = blockIdx.x * blockDim.x + threadIdx.x;
    if (idx >= NG * H2) return;
    int gg = idx / H2, j = idx % H2;
    const float* gp = g + (size_t)gg * H;
    float acc = b[j];
    for (int k = 0; k < H; k++) acc += gp[k] * w[(size_t)k * H2 + j];
    z[idx] = fmaxf(acc, 0.f);
}

__global__ void mlp2(const float* __restrict__ z, const float* __restrict__ w,
                     const float* __restrict__ b, float* __restrict__ out) {
    int idx = blockIdx.x * blockDim.x + threadIdx.x;
    if (idx >= NG * NC) return;
    int gg = idx / NC, c = idx % NC;
    const float* zp = z + (size_t)gg * H2;
    float acc = b[c];
    for (int k = 0; k < H2; k++) acc += zp[k] * w[(size_t)k * NC + c];
    out[idx] = acc;
}

// ---------------- launch ----------------
extern "C" void kernel_launch(void* const* d_in, const int* in_sizes, int n_in,
                              void* d_out, int out_size, void* d_ws, size_t ws_size,
                              hipStream_t stream) {
    (void)d_ws; (void)ws_size;
    const float* x     = (const float*)d_in[0];
    const int*   ei    = (const int*)d_in[1];
    const int*   batch = (const int*)d_in[2];
    const float* w1  = (const float*)d_in[3];  const float* b1  = (const float*)d_in[4];
    const float* w2  = (const float*)d_in[5];  const float* b2  = (const float*)d_in[6];
    const float* w3  = (const float*)d_in[7];  const float* b3  = (const float*)d_in[8];
    const float* wg1 = (const float*)d_in[9];  const float* as1 = (const float*)d_in[10];
    const float* ad1 = (const float*)d_in[11]; const float* bg1 = (const float*)d_in[12];
    const float* wg2 = (const float*)d_in[13]; const float* as2 = (const float*)d_in[14];
    const float* ad2 = (const float*)d_in[15]; const float* bg2 = (const float*)d_in[16];
    const float* wc1 = (const float*)d_in[17]; const float* bc1 = (const float*)d_in[18];
    const float* wc2 = (const float*)d_in[19]; const float* bc2 = (const float*)d_in[20];

    const int* srcp = ei;            // edge_index[0]
    const int* dstp = ei + N_EDGES;  // edge_index[1]

    float *bufB, *dinv, *aS, *aD, *pool, *zb;
    _Float16 *ah, *ch, *wh;
    int *degi, *cursor, *rowptr, *csrsrc;
    hipGetSymbolAddress((void**)&bufB,   HIP_SYMBOL(g_bufB));
    hipGetSymbolAddress((void**)&ah,     HIP_SYMBOL(g_ah));
    hipGetSymbolAddress((void**)&ch,     HIP_SYMBOL(g_ch));
    hipGetSymbolAddress((void**)&wh,     HIP_SYMBOL(g_wh));
    hipGetSymbolAddress((void**)&dinv,   HIP_SYMBOL(g_dinv));
    hipGetSymbolAddress((void**)&degi,   HIP_SYMBOL(g_degi));
    hipGetSymbolAddress((void**)&cursor, HIP_SYMBOL(g_cursor));
    hipGetSymbolAddress((void**)&rowptr, HIP_SYMBOL(g_rowptr));
    hipGetSymbolAddress((void**)&csrsrc, HIP_SYMBOL(g_csrsrc));
    hipGetSymbolAddress((void**)&aS,     HIP_SYMBOL(g_aS));
    hipGetSymbolAddress((void**)&aD,     HIP_SYMBOL(g_aD));
    hipGetSymbolAddress((void**)&pool,   HIP_SYMBOL(g_pool));
    hipGetSymbolAddress((void**)&zb,     HIP_SYMBOL(g_zb));

    auto cdiv = [](int a, int b) { return (a + b - 1) / b; };
    // strips padded to 8-aligned (392) x 6 col tiles; kernel guards spill
    int ggrid = 8 * cdiv(cdiv(N_NODES, 128), 8) * (H / 128);   // 2352

    // ---- CSR build (per call; inputs re-restored each launch) ----
    fill_i32<<<cdiv(N_NODES,256),256,0,stream>>>(degi, N_NODES, 0);
    count_deg<<<cdiv(N_EDGES,256),256,0,stream>>>(dstp, degi);
    dinv_k<<<cdiv(N_NODES,256),256,0,stream>>>(degi, dinv);
    scan_rowptr<<<1,1024,0,stream>>>(degi, rowptr, cursor);
    bin_edges<<<cdiv(N_EDGES,256),256,0,stream>>>(srcp, dstp, cursor, csrsrc);

    // ---- GCN1 (K=3 GEMM stays fp32 vector math, fp16 out) ----
    gemm_k3<<<cdiv(N_NODES*H,256),256,0,stream>>>(x, w1, ch);
    gcn_gather<<<N_NODES,192,0,stream>>>(rowptr, csrsrc, ch, dinv, b1, ah);

    // ---- GCN2 ----
    split_wT<<<cdiv(H*H,256),256,0,stream>>>(w2, wh);
    gemm_f16<<<ggrid,256,0,stream>>>(ah, wh, ch, N_NODES,
                                     (const float*)nullptr, (const float*)nullptr,
                                     (float*)nullptr, (float*)nullptr);
    gcn_gather<<<N_NODES,192,0,stream>>>(rowptr, csrsrc, ch, dinv, b2, ah);

    // ---- GCN3 ----
    split_wT<<<cdiv(H*H,256),256,0,stream>>>(w3, wh);
    gemm_f16<<<ggrid,256,0,stream>>>(ah, wh, ch, N_NODES,
                                     (const float*)nullptr, (const float*)nullptr,
                                     (float*)nullptr, (float*)nullptr);
    gcn_gather<<<N_NODES,192,0,stream>>>(rowptr, csrsrc, ch, dinv, b3, ah);

    // ---- GAT1 (alpha fused into GEMM epilogue) ----
    split_wT<<<cdiv(H*H,256),256,0,stream>>>(wg1, wh);
    gemm_f16<<<ggrid,256,0,stream>>>(ah, wh, ch, N_NODES, as1, ad1, aS, aD);
    gat_gather<<<N_NODES,192,0,stream>>>(rowptr, csrsrc, ch, aS, aD, bg1,
                                         (float*)nullptr, ah, 1);

    // ---- GAT2 (no relu; fp32 out for pooling) ----
    split_wT<<<cdiv(H*H,256),256,0,stream>>>(wg2, wh);
    gemm_f16<<<ggrid,256,0,stream>>>(ah, wh, ch, N_NODES, as2, ad2, aS, aD);
    gat_gather<<<N_NODES,192,0,stream>>>(rowptr, csrsrc, ch, aS, aD, bg2,
                                         bufB, (_Float16*)nullptr, 0);

    // ---- pool + classifier ----
    pool_graph<<<NG,192,0,stream>>>(batch, bufB, pool);
    mlp1<<<cdiv(NG*H2,256),256,0,stream>>>(pool, wc1, bc1, zb);
    mlp2<<<cdiv(NG*NC,64),64,0,stream>>>(zb, wc2, bc2, (float*)d_out);
}

// Round 12
// 1214.999 us; speedup vs baseline: 2.0393x; 1.0847x over previous
//
#include <hip/hip_runtime.h>
#include <math.h>

#define N_NODES 50000
#define N_EDGES 100000
#define H 768
#define NH 12
#define HD 64
#define NG 64
#define NC 10
#define H2 384
#define PCH 32   // pooling chunks per graph (stage-1 parallelism)

typedef _Float16 h8  __attribute__((ext_vector_type(8)));   // 8 fp16 (4 VGPR)
typedef _Float16 h4v __attribute__((ext_vector_type(4)));
typedef float    ffrag __attribute__((ext_vector_type(4))); // MFMA acc

// ---------------- static device scratch ----------------
__device__ float    g_bufB[(size_t)N_NODES * H];   // GAT2 fp32 out (pool input)
__device__ _Float16 g_ah[(size_t)N_NODES * H];     // GEMM input acts fp16
__device__ _Float16 g_ch[(size_t)N_NODES * H];     // GEMM output / gather input fp16
__device__ _Float16 g_wh[H * H];                   // weight^T fp16 [N][K]
__device__ float    g_dinv[N_NODES];
__device__ int      g_degi[N_NODES];
__device__ int      g_cursor[N_NODES];
__device__ int      g_rowptr[N_NODES + 1];
__device__ int      g_csrsrc[N_EDGES];
__device__ float    g_aS[(size_t)N_NODES * NH];
__device__ float    g_aD[(size_t)N_NODES * NH];
__device__ float    g_ppool[(size_t)NG * PCH * H]; // pooling partials (6.3 MB)
__device__ float    g_pool[NG * H];
__device__ float    g_zb[NG * H2];

__device__ inline int clampi(int v, int hi) { return (v < 0) ? 0 : (v >= hi ? hi - 1 : v); }

// async global->LDS, 16B per lane: lane i writes lds_base + i*16 (wave-uniform base)
__device__ inline void gload_lds16(const _Float16* g, _Float16* s) {
    __builtin_amdgcn_global_load_lds(
        (const __attribute__((address_space(1))) void*)g,
        (__attribute__((address_space(3))) void*)s, 16, 0, 0);
}

// ---------------- CSR build ----------------
__global__ void fill_i32(int* p, int n, int v) {
    int i = blockIdx.x * blockDim.x + threadIdx.x;
    if (i < n) p[i] = v;
}

__global__ void count_deg(const int* __restrict__ dst, int* __restrict__ degi) {
    int e = blockIdx.x * blockDim.x + threadIdx.x;
    if (e < N_EDGES) atomicAdd(&degi[clampi(dst[e], N_NODES)], 1);
}

__global__ void dinv_k(const int* __restrict__ degi, float* __restrict__ dinv) {
    int i = blockIdx.x * blockDim.x + threadIdx.x;
    if (i < N_NODES) dinv[i] = rsqrtf((float)degi[i] + 1.0f);   // +1 = self-loop
}

__global__ __launch_bounds__(1024) void scan_rowptr(const int* __restrict__ degi,
                                                    int* __restrict__ rowptr,
                                                    int* __restrict__ cursor) {
    __shared__ int buf[1024];
    __shared__ int carry;
    int tid = threadIdx.x;
    if (tid == 0) carry = 0;
    __syncthreads();
    for (int base = 0; base < N_NODES; base += 1024) {
        int idx = base + tid;
        int v = (idx < N_NODES) ? degi[idx] : 0;
        buf[tid] = v;
        __syncthreads();
        for (int off = 1; off < 1024; off <<= 1) {
            int t = (tid >= off) ? buf[tid - off] : 0;
            __syncthreads();
            buf[tid] += t;
            __syncthreads();
        }
        if (idx < N_NODES) {
            int excl = buf[tid] - v + carry;
            rowptr[idx] = excl;
            cursor[idx] = excl;
        }
        int total = buf[1023];
        __syncthreads();
        if (tid == 0) carry += total;
        __syncthreads();
    }
    if (tid == 0) rowptr[N_NODES] = carry;
}

__global__ void bin_edges(const int* __restrict__ src, const int* __restrict__ dst,
                          int* __restrict__ cursor, int* __restrict__ csrsrc) {
    int e = blockIdx.x * blockDim.x + threadIdx.x;
    if (e >= N_EDGES) return;
    int d = clampi(dst[e], N_NODES);
    int pos = atomicAdd(&cursor[d], 1);
    if (pos >= 0 && pos < N_EDGES) csrsrc[pos] = clampi(src[e], N_NODES);
}

// ---------------- GEMM: x@w1 (K=3), fp16 out ----------------
__global__ void gemm_k3(const float* __restrict__ x, const float* __restrict__ w,
                        _Float16* __restrict__ out) {
    int idx = blockIdx.x * blockDim.x + threadIdx.x;
    if (idx >= N_NODES * H) return;
    int n = idx / H, j = idx % H;
    float x0 = x[n*3], x1 = x[n*3+1], x2 = x[n*3+2];
    out[idx] = (_Float16)(x0 * w[j] + x1 * w[H + j] + x2 * w[2*H + j]);
}

// weights: w[K][N] fp32 -> transposed fp16 [N][K]
__global__ void split_wT(const float* __restrict__ w, _Float16* __restrict__ hi) {
    int idx = blockIdx.x * blockDim.x + threadIdx.x;   // over H*H
    if (idx >= H * H) return;
    int n = idx % H, k = idx / H;                      // read coalesced in n
    hi[(size_t)n * H + k] = (_Float16)w[(size_t)k * H + n];
}

// ---------------- fp16 MFMA GEMM, double-buffered, fp16 C ----------------
// C[M,768] = A[M,768] @ W; fp16 in/out, fp32 MFMA accumulation; W^T [N][K].
// 128x128 tile, 256 threads (4 waves), wave = 64x64 via 4x4 of 16x16x32 MFMA.
// r10: fp16x1 (vs bf16x3): 308->137 us. r11: fp16 C store halves downstream
// traffic. XCD swizzle r6-verified; fused GAT-alpha epilogue r8-verified.
__global__ __launch_bounds__(256) void gemm_f16(const _Float16* __restrict__ a,
                                                const _Float16* __restrict__ bt,
                                                _Float16* __restrict__ C, int M,
                                                const float* __restrict__ asf,
                                                const float* __restrict__ adf,
                                                float* __restrict__ aS,
                                                float* __restrict__ aD) {
    __shared__ _Float16 sA[2][128 * 32], sB[2][128 * 32];
    int tid = threadIdx.x;
    int wave = tid >> 6, lane = tid & 63;
    int quad = lane >> 4, l16 = lane & 15;

    int id = blockIdx.x;
    int x = id & 7;
    int s = id >> 3;
    int strip = x + 8 * (s / 6);
    int colt = s % 6;
    if (strip >= (N_NODES + 127) / 128) return;
    int row0 = strip * 128, col0 = colt * 128;
    int wr = (wave >> 1) * 64, wc = (wave & 1) * 64;

    // staging: waves 0,1 -> A segs 0-3 / 4-7; waves 2,3 -> B segs 0-3 / 4-7
    int isA = (wave < 2);
    const _Float16* gsrc = isA ? a : bt;
    int gbase = isA ? row0 : col0;
    int segbase = (wave & 1) * 4;
    int rr = lane >> 2, kc = (lane & 3) << 3;   // 4 lanes/row, 8-half chunks
    const _Float16* gptr[4];
    int soff[4];
    #pragma unroll
    for (int k = 0; k < 4; k++) {
        int seg = segbase + k;
        int r = gbase + seg * 16 + rr;
        if (isA && r >= M) r = M - 1;   // clamped rows feed unstored C rows
        gptr[k] = gsrc + (size_t)r * H + kc;
        soff[k] = seg * 512;
    }
    _Float16* sd0 = isA ? sA[0] : sB[0];
    _Float16* sd1 = isA ? sA[1] : sB[1];

    ffrag acc[4][4];
    #pragma unroll
    for (int i = 0; i < 4; i++)
        #pragma unroll
        for (int j = 0; j < 4; j++) { ffrag z = {0.f, 0.f, 0.f, 0.f}; acc[i][j] = z; }

    // prologue: stage k-tile 0 into buf 0
    #pragma unroll
    for (int k = 0; k < 4; k++)
        gload_lds16(gptr[k], sd0 + soff[k]);

    #pragma unroll 1
    for (int kt = 0; kt < H / 32; kt++) {
        int cur = kt & 1;
        __syncthreads();   // buf[cur] loads complete (compiler vmcnt drain)
        if (kt + 1 < H / 32) {
            _Float16* nb = cur ? sd0 : sd1;
            int koff = (kt + 1) * 32;
            #pragma unroll
            for (int k = 0; k < 4; k++)
                gload_lds16(gptr[k] + koff, nb + soff[k]);
        }

        const _Float16* pA = sA[cur];
        const _Float16* pB = sB[cur];
        h8 fa[4], fb[4];
        #pragma unroll
        for (int i = 0; i < 4; i++)
            fa[i] = *reinterpret_cast<const h8*>(&pA[(wr + i * 16 + l16) * 32 + quad * 8]);
        #pragma unroll
        for (int j = 0; j < 4; j++)
            fb[j] = *reinterpret_cast<const h8*>(&pB[(wc + j * 16 + l16) * 32 + quad * 8]);
        #pragma unroll
        for (int i = 0; i < 4; i++)
            #pragma unroll
            for (int j = 0; j < 4; j++)
                acc[i][j] = __builtin_amdgcn_mfma_f32_16x16x32_f16(fa[i], fb[j], acc[i][j], 0, 0, 0);
    }

    // epilogue: C/D layout col=lane&15, row=quad*4+reg (m89-verified); fp16 store
    #pragma unroll
    for (int i = 0; i < 4; i++)
        #pragma unroll
        for (int r = 0; r < 4; r++) {
            int row = row0 + wr + i * 16 + quad * 4 + r;
            if (row >= M) continue;
            #pragma unroll
            for (int j = 0; j < 4; j++)
                C[(size_t)row * H + col0 + wc + j * 16 + l16] = (_Float16)acc[i][j][r];
        }

    // fused GAT alpha: this wave covers one full head (64 cols) for 64 rows
    if (asf) {
        int head = (col0 + wc) >> 6;
        float as_c[4], ad_c[4];
        #pragma unroll
        for (int j = 0; j < 4; j++) {
            int col = col0 + wc + j * 16 + l16;
            as_c[j] = asf[col];
            ad_c[j] = adf[col];
        }
        #pragma unroll
        for (int i = 0; i < 4; i++)
            #pragma unroll
            for (int r = 0; r < 4; r++) {
                float ps = 0.f, pd = 0.f;
                #pragma unroll
                for (int j = 0; j < 4; j++) {
                    ps += acc[i][j][r] * as_c[j];
                    pd += acc[i][j][r] * ad_c[j];
                }
                ps += __shfl_xor(ps, 1);  pd += __shfl_xor(pd, 1);
                ps += __shfl_xor(ps, 2);  pd += __shfl_xor(pd, 2);
                ps += __shfl_xor(ps, 4);  pd += __shfl_xor(pd, 4);
                ps += __shfl_xor(ps, 8);  pd += __shfl_xor(pd, 8);
                int row = row0 + wr + i * 16 + quad * 4 + r;
                if (l16 == 0 && row < M) {
                    aS[row * NH + head] = ps;
                    aD[row * NH + head] = pd;
                }
            }
    }
}

// ---------------- fused GCN gather: fp16 in, fp32 accum, fp16 out ----------------
__global__ void gcn_gather(const int* __restrict__ rowptr, const int* __restrict__ csrsrc,
                           const _Float16* __restrict__ h, const float* __restrict__ dinv,
                           const float* __restrict__ bias, _Float16* __restrict__ hi) {
    int d = blockIdx.x;
    int t = threadIdx.x;   // 0..191, 4 halves each
    float dd = dinv[d];
    h4v v = ((const h4v*)(h + (size_t)d * H))[t];
    float c = dd * dd;
    float ax = (float)v[0] * c, ay = (float)v[1] * c, az = (float)v[2] * c, aw = (float)v[3] * c;
    int beg = rowptr[d], end = rowptr[d + 1];
    for (int i = beg; i < end; i++) {
        int s = csrsrc[i];
        float cc = dinv[s] * dd;
        h4v u = ((const h4v*)(h + (size_t)s * H))[t];
        ax += (float)u[0] * cc; ay += (float)u[1] * cc;
        az += (float)u[2] * cc; aw += (float)u[3] * cc;
    }
    float4 b = ((const float4*)bias)[t];
    h4v o;
    o[0] = (_Float16)fmaxf(ax + b.x, 0.f);
    o[1] = (_Float16)fmaxf(ay + b.y, 0.f);
    o[2] = (_Float16)fmaxf(az + b.z, 0.f);
    o[3] = (_Float16)fmaxf(aw + b.w, 0.f);
    ((h4v*)(hi + (size_t)d * H))[t] = o;
}

__device__ inline float lrelu(float v) { return (v > 0.f) ? v : 0.2f * v; }

// fused softmax + weighted aggregation + bias (+relu); one block per dst node.
// hi nonnull -> write fp16 (next GEMM input); else fp32 to out (pooling).
__global__ void gat_gather(const int* __restrict__ rowptr, const int* __restrict__ csrsrc,
                           const _Float16* __restrict__ h, const float* __restrict__ aS,
                           const float* __restrict__ aD, const float* __restrict__ bias,
                           float* __restrict__ out, _Float16* __restrict__ hi, int relu) {
    int d = blockIdx.x;
    int t = threadIdx.x;
    int hh = t >> 4;
    int beg = rowptr[d], end = rowptr[d + 1];
    float adv = aD[d * NH + hh];
    float eself = lrelu(aS[d * NH + hh] + adv);
    float m = eself;
    for (int i = beg; i < end; i++)
        m = fmaxf(m, lrelu(aS[csrsrc[i] * NH + hh] + adv));
    float ssum = __expf(eself - m);
    for (int i = beg; i < end; i++)
        ssum += __expf(lrelu(aS[csrsrc[i] * NH + hh] + adv) - m);
    float inv = 1.0f / ssum;
    float cself = __expf(eself - m) * inv;
    h4v v = ((const h4v*)(h + (size_t)d * H))[t];
    float ax = (float)v[0] * cself, ay = (float)v[1] * cself;
    float az = (float)v[2] * cself, aw = (float)v[3] * cself;
    for (int i = beg; i < end; i++) {
        int s = csrsrc[i];
        float c = __expf(lrelu(aS[s * NH + hh] + adv) - m) * inv;
        h4v u = ((const h4v*)(h + (size_t)s * H))[t];
        ax += (float)u[0] * c; ay += (float)u[1] * c;
        az += (float)u[2] * c; aw += (float)u[3] * c;
    }
    float4 b = ((const float4*)bias)[t];
    ax += b.x; ay += b.y; az += b.z; aw += b.w;
    if (relu) {
        ax = fmaxf(ax, 0.f); ay = fmaxf(ay, 0.f);
        az = fmaxf(az, 0.f); aw = fmaxf(aw, 0.f);
    }
    if (hi) {
        h4v o;
        o[0] = (_Float16)ax; o[1] = (_Float16)ay;
        o[2] = (_Float16)az; o[3] = (_Float16)aw;
        ((h4v*)(hi + (size_t)d * H))[t] = o;
    } else {
        float4 o; o.x = ax; o.y = ay; o.z = az; o.w = aw;
        ((float4*)(out + (size_t)d * H))[t] = o;
    }
}

// ---------------- pooling (batch is sorted), two-stage ----------------
__device__ inline int lower_bound_i(const int* b, int n, int key) {
    int lo = 0, hi = n;
    while (lo < hi) { int mid = (lo + hi) >> 1; if (b[mid] < key) lo = mid + 1; else hi = mid; }
    return lo;
}

// stage 1: block (g, c) sums its 1/PCH slice of graph g's rows -> ppool.
// r11 evidence: single-stage pool_graph had 64 blocks = 1.5% occupancy, 144 us.
__global__ void pool_partial(const int* __restrict__ batch, const float* __restrict__ h,
                             float* __restrict__ ppool) {
    int g = blockIdx.x / PCH, c = blockIdx.x % PCH;
    int t = threadIdx.x;   // 0..191
    int lo = lower_bound_i(batch, N_NODES, g);
    int hi = lower_bound_i(batch, N_NODES, g + 1);
    int len = hi - lo;
    int chunk = (len + PCH - 1) / PCH;
    int s = lo + c * chunk;
    int e = s + chunk; if (e > hi) e = hi;
    float4 a = {0, 0, 0, 0};
    for (int n = s; n < e; n++) {
        float4 v = ((const float4*)(h + (size_t)n * H))[t];
        a.x += v.x; a.y += v.y; a.z += v.z; a.w += v.w;
    }
    ((float4*)(ppool + (size_t)blockIdx.x * H))[t] = a;
}

// stage 2: reduce PCH partials per graph, divide by count
__global__ void pool_final(const int* __restrict__ batch, const float* __restrict__ ppool,
                           float* __restrict__ pool) {
    int g = blockIdx.x;
    int t = threadIdx.x;
    int lo = lower_bound_i(batch, N_NODES, g);
    int hi = lower_bound_i(batch, N_NODES, g + 1);
    float4 a = {0, 0, 0, 0};
    for (int c = 0; c < PCH; c++) {
        float4 v = ((const float4*)(ppool + (size_t)(g * PCH + c) * H))[t];
        a.x += v.x; a.y += v.y; a.z += v.z; a.w += v.w;
    }
    float inv = 1.0f / fmaxf((float)(hi - lo), 1.0f);
    float4 o; o.x = a.x * inv; o.y = a.y * inv; o.z = a.z * inv; o.w = a.w * inv;
    ((float4*)(pool + (size_t)g * H))[t] = o;
}

__global__ void mlp1(const float* __restrict__ g, const float* __restrict__ w,
                     const float* __restrict__ b, float* __restrict__ z) {
    int idx = blockIdx.x * blockDim.x + threadIdx.x;
    if (idx >= NG * H2) return;
    int gg = idx / H2, j = idx % H2;
    const float* gp = g + (size_t)gg * H;
    float acc = b[j];
    for (int k = 0; k < H; k++) acc += gp[k] * w[(size_t)k * H2 + j];
    z[idx] = fmaxf(acc, 0.f);
}

__global__ void mlp2(const float* __restrict__ z, const float* __restrict__ w,
                     const float* __restrict__ b, float* __restrict__ out) {
    int idx = blockIdx.x * blockDim.x + threadIdx.x;
    if (idx >= NG * NC) return;
    int gg = idx / NC, c = idx % NC;
    const float* zp = z + (size_t)gg * H2;
    float acc = b[c];
    for (int k = 0; k < H2; k++) acc += zp[k] * w[(size_t)k * NC + c];
    out[idx] = acc;
}

// ---------------- launch ----------------
extern "C" void kernel_launch(void* const* d_in, const int* in_sizes, int n_in,
                              void* d_out, int out_size, void* d_ws, size_t ws_size,
                              hipStream_t stream) {
    (void)d_ws; (void)ws_size;
    const float* x     = (const float*)d_in[0];
    const int*   ei    = (const int*)d_in[1];
    const int*   batch = (const int*)d_in[2];
    const float* w1  = (const float*)d_in[3];  const float* b1  = (const float*)d_in[4];
    const float* w2  = (const float*)d_in[5];  const float* b2  = (const float*)d_in[6];
    const float* w3  = (const float*)d_in[7];  const float* b3  = (const float*)d_in[8];
    const float* wg1 = (const float*)d_in[9];  const float* as1 = (const float*)d_in[10];
    const float* ad1 = (const float*)d_in[11]; const float* bg1 = (const float*)d_in[12];
    const float* wg2 = (const float*)d_in[13]; const float* as2 = (const float*)d_in[14];
    const float* ad2 = (const float*)d_in[15]; const float* bg2 = (const float*)d_in[16];
    const float* wc1 = (const float*)d_in[17]; const float* bc1 = (const float*)d_in[18];
    const float* wc2 = (const float*)d_in[19]; const float* bc2 = (const float*)d_in[20];

    const int* srcp = ei;            // edge_index[0]
    const int* dstp = ei + N_EDGES;  // edge_index[1]

    float *bufB, *dinv, *aS, *aD, *ppool, *pool, *zb;
    _Float16 *ah, *ch, *wh;
    int *degi, *cursor, *rowptr, *csrsrc;
    hipGetSymbolAddress((void**)&bufB,   HIP_SYMBOL(g_bufB));
    hipGetSymbolAddress((void**)&ah,     HIP_SYMBOL(g_ah));
    hipGetSymbolAddress((void**)&ch,     HIP_SYMBOL(g_ch));
    hipGetSymbolAddress((void**)&wh,     HIP_SYMBOL(g_wh));
    hipGetSymbolAddress((void**)&dinv,   HIP_SYMBOL(g_dinv));
    hipGetSymbolAddress((void**)&degi,   HIP_SYMBOL(g_degi));
    hipGetSymbolAddress((void**)&cursor, HIP_SYMBOL(g_cursor));
    hipGetSymbolAddress((void**)&rowptr, HIP_SYMBOL(g_rowptr));
    hipGetSymbolAddress((void**)&csrsrc, HIP_SYMBOL(g_csrsrc));
    hipGetSymbolAddress((void**)&aS,     HIP_SYMBOL(g_aS));
    hipGetSymbolAddress((void**)&aD,     HIP_SYMBOL(g_aD));
    hipGetSymbolAddress((void**)&ppool,  HIP_SYMBOL(g_ppool));
    hipGetSymbolAddress((void**)&pool,   HIP_SYMBOL(g_pool));
    hipGetSymbolAddress((void**)&zb,     HIP_SYMBOL(g_zb));

    auto cdiv = [](int a, int b) { return (a + b - 1) / b; };
    // strips padded to 8-aligned (392) x 6 col tiles; kernel guards spill
    int ggrid = 8 * cdiv(cdiv(N_NODES, 128), 8) * (H / 128);   // 2352

    // ---- CSR build (per call; inputs re-restored each launch) ----
    fill_i32<<<cdiv(N_NODES,256),256,0,stream>>>(degi, N_NODES, 0);
    count_deg<<<cdiv(N_EDGES,256),256,0,stream>>>(dstp, degi);
    dinv_k<<<cdiv(N_NODES,256),256,0,stream>>>(degi, dinv);
    scan_rowptr<<<1,1024,0,stream>>>(degi, rowptr, cursor);
    bin_edges<<<cdiv(N_EDGES,256),256,0,stream>>>(srcp, dstp, cursor, csrsrc);

    // ---- GCN1 (K=3 GEMM stays fp32 vector math, fp16 out) ----
    gemm_k3<<<cdiv(N_NODES*H,256),256,0,stream>>>(x, w1, ch);
    gcn_gather<<<N_NODES,192,0,stream>>>(rowptr, csrsrc, ch, dinv, b1, ah);

    // ---- GCN2 ----
    split_wT<<<cdiv(H*H,256),256,0,stream>>>(w2, wh);
    gemm_f16<<<ggrid,256,0,stream>>>(ah, wh, ch, N_NODES,
                                     (const float*)nullptr, (const float*)nullptr,
                                     (float*)nullptr, (float*)nullptr);
    gcn_gather<<<N_NODES,192,0,stream>>>(rowptr, csrsrc, ch, dinv, b2, ah);

    // ---- GCN3 ----
    split_wT<<<cdiv(H*H,256),256,0,stream>>>(w3, wh);
    gemm_f16<<<ggrid,256,0,stream>>>(ah, wh, ch, N_NODES,
                                     (const float*)nullptr, (const float*)nullptr,
                                     (float*)nullptr, (float*)nullptr);
    gcn_gather<<<N_NODES,192,0,stream>>>(rowptr, csrsrc, ch, dinv, b3, ah);

    // ---- GAT1 (alpha fused into GEMM epilogue) ----
    split_wT<<<cdiv(H*H,256),256,0,stream>>>(wg1, wh);
    gemm_f16<<<ggrid,256,0,stream>>>(ah, wh, ch, N_NODES, as1, ad1, aS, aD);
    gat_gather<<<N_NODES,192,0,stream>>>(rowptr, csrsrc, ch, aS, aD, bg1,
                                         (float*)nullptr, ah, 1);

    // ---- GAT2 (no relu; fp32 out for pooling) ----
    split_wT<<<cdiv(H*H,256),256,0,stream>>>(wg2, wh);
    gemm_f16<<<ggrid,256,0,stream>>>(ah, wh, ch, N_NODES, as2, ad2, aS, aD);
    gat_gather<<<N_NODES,192,0,stream>>>(rowptr, csrsrc, ch, aS, aD, bg2,
                                         bufB, (_Float16*)nullptr, 0);

    // ---- pool (two-stage) + classifier ----
    pool_partial<<<NG*PCH,192,0,stream>>>(batch, bufB, ppool);
    pool_final<<<NG,192,0,stream>>>(batch, ppool, pool);
    mlp1<<<cdiv(NG*H2,256),256,0,stream>>>(pool, wc1, bc1, zb);
    mlp2<<<cdiv(NG*NC,64),64,0,stream>>>(zb, wc2, bc2, (float*)d_out);
}

// Round 13
// 1089.869 us; speedup vs baseline: 2.2734x; 1.1148x over previous
//
#include <hip/hip_runtime.h>
#include <math.h>

#define N_NODES 50000
#define N_EDGES 100000
#define H 768
#define NH 12
#define HD 64
#define NG 64
#define NC 10
#define H2 384
#define PCH 32   // pooling chunks per graph
#define NSB 196  // scan blocks = cdiv(N_NODES,256)

typedef _Float16 h8  __attribute__((ext_vector_type(8)));   // 8 fp16 (4 VGPR)
typedef _Float16 h4v __attribute__((ext_vector_type(4)));
typedef float    ffrag __attribute__((ext_vector_type(4))); // MFMA acc

// ---------------- static device scratch ----------------
__device__ float    g_bufB[(size_t)N_NODES * H];   // GAT2 fp32 out (pool input)
__device__ _Float16 g_ah[(size_t)N_NODES * H];     // GEMM input acts fp16
__device__ _Float16 g_ch[(size_t)N_NODES * H];     // GEMM output / gather input fp16
__device__ _Float16 g_wh[4 * H * H];               // 4 weights^T fp16 [N][K]
__device__ float    g_dinv[N_NODES];
__device__ int      g_degi[N_NODES];
__device__ int      g_bsum[256];
__device__ int      g_boff[256];
__device__ int      g_cursor[N_NODES];
__device__ int      g_rowptr[N_NODES + 1];
__device__ int      g_csrsrc[N_EDGES];
__device__ float    g_aS[(size_t)N_NODES * NH];
__device__ float    g_aD[(size_t)N_NODES * NH];
__device__ float    g_ppool[(size_t)NG * PCH * H]; // pooling partials (6.3 MB)
__device__ float    g_zb[NG * H2];

__device__ inline int clampi(int v, int hi) { return (v < 0) ? 0 : (v >= hi ? hi - 1 : v); }

// async global->LDS, 16B per lane: lane i writes lds_base + i*16 (wave-uniform base)
__device__ inline void gload_lds16(const _Float16* g, _Float16* s) {
    __builtin_amdgcn_global_load_lds(
        (const __attribute__((address_space(1))) void*)g,
        (__attribute__((address_space(3))) void*)s, 16, 0, 0);
}

// ---------------- CSR build ----------------
__global__ void fill_i32(int* p, int n, int v) {
    int i = blockIdx.x * blockDim.x + threadIdx.x;
    if (i < n) p[i] = v;
}

__global__ void count_deg(const int* __restrict__ dst, int* __restrict__ degi) {
    int e = blockIdx.x * blockDim.x + threadIdx.x;
    if (e < N_EDGES) atomicAdd(&degi[clampi(dst[e], N_NODES)], 1);
}

// hierarchical scan (replaces r12's single-block scan_rowptr, ~1000 barriers)
__global__ __launch_bounds__(256) void scan1(const int* __restrict__ degi, int* __restrict__ bsum) {
    __shared__ int s[256];
    int b = blockIdx.x, t = threadIdx.x;
    int idx = b * 256 + t;
    s[t] = (idx < N_NODES) ? degi[idx] : 0;
    __syncthreads();
    for (int off = 128; off > 0; off >>= 1) {
        if (t < off) s[t] += s[t + off];
        __syncthreads();
    }
    if (t == 0) bsum[b] = s[0];
}

__global__ __launch_bounds__(256) void scan2(const int* __restrict__ bsum, int* __restrict__ boff,
                                             int* __restrict__ rowptr) {
    __shared__ int s[256];
    int t = threadIdx.x;
    int v = (t < NSB) ? bsum[t] : 0;
    s[t] = v;
    __syncthreads();
    for (int off = 1; off < 256; off <<= 1) {
        int x = (t >= off) ? s[t - off] : 0;
        __syncthreads();
        s[t] += x;
        __syncthreads();
    }
    if (t < NSB) boff[t] = s[t] - v;          // exclusive block offset
    if (t == NSB - 1) rowptr[N_NODES] = s[t]; // total
}

// local scan + write rowptr/cursor; dinv fused (reads degi anyway)
__global__ __launch_bounds__(256) void scan3(const int* __restrict__ degi, const int* __restrict__ boff,
                                             int* __restrict__ rowptr, int* __restrict__ cursor,
                                             float* __restrict__ dinv) {
    __shared__ int s[256];
    int b = blockIdx.x, t = threadIdx.x;
    int idx = b * 256 + t;
    int v = (idx < N_NODES) ? degi[idx] : 0;
    s[t] = v;
    __syncthreads();
    for (int off = 1; off < 256; off <<= 1) {
        int x = (t >= off) ? s[t - off] : 0;
        __syncthreads();
        s[t] += x;
        __syncthreads();
    }
    if (idx < N_NODES) {
        int excl = s[t] - v + boff[b];
        rowptr[idx] = excl;
        cursor[idx] = excl;
        dinv[idx] = rsqrtf((float)v + 1.0f);   // +1 = self-loop
    }
}

__global__ void bin_edges(const int* __restrict__ src, const int* __restrict__ dst,
                          int* __restrict__ cursor, int* __restrict__ csrsrc) {
    int e = blockIdx.x * blockDim.x + threadIdx.x;
    if (e >= N_EDGES) return;
    int d = clampi(dst[e], N_NODES);
    int pos = atomicAdd(&cursor[d], 1);
    if (pos >= 0 && pos < N_EDGES) csrsrc[pos] = clampi(src[e], N_NODES);
}

// ---------------- GEMM: x@w1 (K=3), fp16 out ----------------
__global__ void gemm_k3(const float* __restrict__ x, const float* __restrict__ w,
                        _Float16* __restrict__ out) {
    int idx = blockIdx.x * blockDim.x + threadIdx.x;
    if (idx >= N_NODES * H) return;
    int n = idx / H, j = idx % H;
    float x0 = x[n*3], x1 = x[n*3+1], x2 = x[n*3+2];
    out[idx] = (_Float16)(x0 * w[j] + x1 * w[H + j] + x2 * w[2*H + j]);
}

// all 4 big weights: w[K][N] fp32 -> transposed fp16 [N][K], one launch (off critical path)
__global__ void split_wT4(const float* __restrict__ w2, const float* __restrict__ w3,
                          const float* __restrict__ wg1, const float* __restrict__ wg2,
                          _Float16* __restrict__ out) {
    int idx = blockIdx.x * blockDim.x + threadIdx.x;
    if (idx >= 4 * H * H) return;
    int l = idx / (H * H), r = idx % (H * H);
    const float* w = (l == 0) ? w2 : (l == 1) ? w3 : (l == 2) ? wg1 : wg2;
    int n = r % H, k = r / H;
    out[(size_t)l * H * H + (size_t)n * H + k] = (_Float16)w[(size_t)k * H + n];
}

// ---------------- fp16 MFMA GEMM, double-buffered, fp16 C ----------------
// C[M,768] = A[M,768] @ W; fp16 in/out, fp32 MFMA accumulation; W^T [N][K].
// 128x128 tile, 256 threads (4 waves), wave = 64x64 via 4x4 of 16x16x32 MFMA.
// r10: fp16x1: 308->137 us. r11: fp16 C store. XCD swizzle r6-verified; fused
// GAT-alpha epilogue r8-verified. Structure at its HIP-level plateau: the
// compiler's vmcnt(0)+s_barrier drains any deeper prefetch (r7/r8 evidence).
__global__ __launch_bounds__(256) void gemm_f16(const _Float16* __restrict__ a,
                                                const _Float16* __restrict__ bt,
                                                _Float16* __restrict__ C, int M,
                                                const float* __restrict__ asf,
                                                const float* __restrict__ adf,
                                                float* __restrict__ aS,
                                                float* __restrict__ aD) {
    __shared__ _Float16 sA[2][128 * 32], sB[2][128 * 32];
    int tid = threadIdx.x;
    int wave = tid >> 6, lane = tid & 63;
    int quad = lane >> 4, l16 = lane & 15;

    int id = blockIdx.x;
    int x = id & 7;
    int s = id >> 3;
    int strip = x + 8 * (s / 6);
    int colt = s % 6;
    if (strip >= (N_NODES + 127) / 128) return;
    int row0 = strip * 128, col0 = colt * 128;
    int wr = (wave >> 1) * 64, wc = (wave & 1) * 64;

    // staging: waves 0,1 -> A segs 0-3 / 4-7; waves 2,3 -> B segs 0-3 / 4-7
    int isA = (wave < 2);
    const _Float16* gsrc = isA ? a : bt;
    int gbase = isA ? row0 : col0;
    int segbase = (wave & 1) * 4;
    int rr = lane >> 2, kc = (lane & 3) << 3;   // 4 lanes/row, 8-half chunks
    const _Float16* gptr[4];
    int soff[4];
    #pragma unroll
    for (int k = 0; k < 4; k++) {
        int seg = segbase + k;
        int r = gbase + seg * 16 + rr;
        if (isA && r >= M) r = M - 1;   // clamped rows feed unstored C rows
        gptr[k] = gsrc + (size_t)r * H + kc;
        soff[k] = seg * 512;
    }
    _Float16* sd0 = isA ? sA[0] : sB[0];
    _Float16* sd1 = isA ? sA[1] : sB[1];

    ffrag acc[4][4];
    #pragma unroll
    for (int i = 0; i < 4; i++)
        #pragma unroll
        for (int j = 0; j < 4; j++) { ffrag z = {0.f, 0.f, 0.f, 0.f}; acc[i][j] = z; }

    // prologue: stage k-tile 0 into buf 0
    #pragma unroll
    for (int k = 0; k < 4; k++)
        gload_lds16(gptr[k], sd0 + soff[k]);

    #pragma unroll 1
    for (int kt = 0; kt < H / 32; kt++) {
        int cur = kt & 1;
        __syncthreads();   // buf[cur] loads complete (compiler vmcnt drain)
        if (kt + 1 < H / 32) {
            _Float16* nb = cur ? sd0 : sd1;
            int koff = (kt + 1) * 32;
            #pragma unroll
            for (int k = 0; k < 4; k++)
                gload_lds16(gptr[k] + koff, nb + soff[k]);
        }

        const _Float16* pA = sA[cur];
        const _Float16* pB = sB[cur];
        h8 fa[4], fb[4];
        #pragma unroll
        for (int i = 0; i < 4; i++)
            fa[i] = *reinterpret_cast<const h8*>(&pA[(wr + i * 16 + l16) * 32 + quad * 8]);
        #pragma unroll
        for (int j = 0; j < 4; j++)
            fb[j] = *reinterpret_cast<const h8*>(&pB[(wc + j * 16 + l16) * 32 + quad * 8]);
        #pragma unroll
        for (int i = 0; i < 4; i++)
            #pragma unroll
            for (int j = 0; j < 4; j++)
                acc[i][j] = __builtin_amdgcn_mfma_f32_16x16x32_f16(fa[i], fb[j], acc[i][j], 0, 0, 0);
    }

    // epilogue: C/D layout col=lane&15, row=quad*4+reg (m89-verified); fp16 store
    #pragma unroll
    for (int i = 0; i < 4; i++)
        #pragma unroll
        for (int r = 0; r < 4; r++) {
            int row = row0 + wr + i * 16 + quad * 4 + r;
            if (row >= M) continue;
            #pragma unroll
            for (int j = 0; j < 4; j++)
                C[(size_t)row * H + col0 + wc + j * 16 + l16] = (_Float16)acc[i][j][r];
        }

    // fused GAT alpha: this wave covers one full head (64 cols) for 64 rows
    if (asf) {
        int head = (col0 + wc) >> 6;
        float as_c[4], ad_c[4];
        #pragma unroll
        for (int j = 0; j < 4; j++) {
            int col = col0 + wc + j * 16 + l16;
            as_c[j] = asf[col];
            ad_c[j] = adf[col];
        }
        #pragma unroll
        for (int i = 0; i < 4; i++)
            #pragma unroll
            for (int r = 0; r < 4; r++) {
                float ps = 0.f, pd = 0.f;
                #pragma unroll
                for (int j = 0; j < 4; j++) {
                    ps += acc[i][j][r] * as_c[j];
                    pd += acc[i][j][r] * ad_c[j];
                }
                ps += __shfl_xor(ps, 1);  pd += __shfl_xor(pd, 1);
                ps += __shfl_xor(ps, 2);  pd += __shfl_xor(pd, 2);
                ps += __shfl_xor(ps, 4);  pd += __shfl_xor(pd, 4);
                ps += __shfl_xor(ps, 8);  pd += __shfl_xor(pd, 8);
                int row = row0 + wr + i * 16 + quad * 4 + r;
                if (l16 == 0 && row < M) {
                    aS[row * NH + head] = ps;
                    aD[row * NH + head] = pd;
                }
            }
    }
}

// ---------------- fused GCN gather: fp16 in, fp32 accum, fp16 out ----------------
__global__ void gcn_gather(const int* __restrict__ rowptr, const int* __restrict__ csrsrc,
                           const _Float16* __restrict__ h, const float* __restrict__ dinv,
                           const float* __restrict__ bias, _Float16* __restrict__ hi) {
    int d = blockIdx.x;
    int t = threadIdx.x;   // 0..191, 4 halves each
    float dd = dinv[d];
    h4v v = ((const h4v*)(h + (size_t)d * H))[t];
    float c = dd * dd;
    float ax = (float)v[0] * c, ay = (float)v[1] * c, az = (float)v[2] * c, aw = (float)v[3] * c;
    int beg = rowptr[d], end = rowptr[d + 1];
    for (int i = beg; i < end; i++) {
        int s = csrsrc[i];
        float cc = dinv[s] * dd;
        h4v u = ((const h4v*)(h + (size_t)s * H))[t];
        ax += (float)u[0] * cc; ay += (float)u[1] * cc;
        az += (float)u[2] * cc; aw += (float)u[3] * cc;
    }
    float4 b = ((const float4*)bias)[t];
    h4v o;
    o[0] = (_Float16)fmaxf(ax + b.x, 0.f);
    o[1] = (_Float16)fmaxf(ay + b.y, 0.f);
    o[2] = (_Float16)fmaxf(az + b.z, 0.f);
    o[3] = (_Float16)fmaxf(aw + b.w, 0.f);
    ((h4v*)(hi + (size_t)d * H))[t] = o;
}

__device__ inline float lrelu(float v) { return (v > 0.f) ? v : 0.2f * v; }

// fused softmax + weighted aggregation + bias (+relu); one block per dst node.
// hi nonnull -> write fp16 (next GEMM input); else fp32 to out (pooling).
__global__ void gat_gather(const int* __restrict__ rowptr, const int* __restrict__ csrsrc,
                           const _Float16* __restrict__ h, const float* __restrict__ aS,
                           const float* __restrict__ aD, const float* __restrict__ bias,
                           float* __restrict__ out, _Float16* __restrict__ hi, int relu) {
    int d = blockIdx.x;
    int t = threadIdx.x;
    int hh = t >> 4;
    int beg = rowptr[d], end = rowptr[d + 1];
    float adv = aD[d * NH + hh];
    float eself = lrelu(aS[d * NH + hh] + adv);
    float m = eself;
    for (int i = beg; i < end; i++)
        m = fmaxf(m, lrelu(aS[csrsrc[i] * NH + hh] + adv));
    float ssum = __expf(eself - m);
    for (int i = beg; i < end; i++)
        ssum += __expf(lrelu(aS[csrsrc[i] * NH + hh] + adv) - m);
    float inv = 1.0f / ssum;
    float cself = __expf(eself - m) * inv;
    h4v v = ((const h4v*)(h + (size_t)d * H))[t];
    float ax = (float)v[0] * cself, ay = (float)v[1] * cself;
    float az = (float)v[2] * cself, aw = (float)v[3] * cself;
    for (int i = beg; i < end; i++) {
        int s = csrsrc[i];
        float c = __expf(lrelu(aS[s * NH + hh] + adv) - m) * inv;
        h4v u = ((const h4v*)(h + (size_t)s * H))[t];
        ax += (float)u[0] * c; ay += (float)u[1] * c;
        az += (float)u[2] * c; aw += (float)u[3] * c;
    }
    float4 b = ((const float4*)bias)[t];
    ax += b.x; ay += b.y; az += b.z; aw += b.w;
    if (relu) {
        ax = fmaxf(ax, 0.f); ay = fmaxf(ay, 0.f);
        az = fmaxf(az, 0.f); aw = fmaxf(aw, 0.f);
    }
    if (hi) {
        h4v o;
        o[0] = (_Float16)ax; o[1] = (_Float16)ay;
        o[2] = (_Float16)az; o[3] = (_Float16)aw;
        ((h4v*)(hi + (size_t)d * H))[t] = o;
    } else {
        float4 o; o.x = ax; o.y = ay; o.z = az; o.w = aw;
        ((float4*)(out + (size_t)d * H))[t] = o;
    }
}

// ---------------- pooling (batch is sorted), two-stage + fused mlp1 ----------------
__device__ inline int lower_bound_i(const int* b, int n, int key) {
    int lo = 0, hi = n;
    while (lo < hi) { int mid = (lo + hi) >> 1; if (b[mid] < key) lo = mid + 1; else hi = mid; }
    return lo;
}

// stage 1: block (g, c) sums its 1/PCH slice of graph g's rows -> ppool.
__global__ void pool_partial(const int* __restrict__ batch, const float* __restrict__ h,
                             float* __restrict__ ppool) {
    int g = blockIdx.x / PCH, c = blockIdx.x % PCH;
    int t = threadIdx.x;   // 0..191
    int lo = lower_bound_i(batch, N_NODES, g);
    int hi = lower_bound_i(batch, N_NODES, g + 1);
    int len = hi - lo;
    int chunk = (len + PCH - 1) / PCH;
    int s = lo + c * chunk;
    int e = s + chunk; if (e > hi) e = hi;
    float4 a = {0, 0, 0, 0};
    for (int n = s; n < e; n++) {
        float4 v = ((const float4*)(h + (size_t)n * H))[t];
        a.x += v.x; a.y += v.y; a.z += v.z; a.w += v.w;
    }
    ((float4*)(ppool + (size_t)blockIdx.x * H))[t] = a;
}

// stage 2 fused with mlp1: reduce PCH partials into LDS row, then z = relu(row@wc1+bc1)
__global__ __launch_bounds__(384) void pool_mlp1(const int* __restrict__ batch,
                                                 const float* __restrict__ ppool,
                                                 const float* __restrict__ wc1,
                                                 const float* __restrict__ bc1,
                                                 float* __restrict__ z) {
    __shared__ float row[H];
    int g = blockIdx.x, t = threadIdx.x;   // 384 threads
    int lo = lower_bound_i(batch, N_NODES, g);
    int hi = lower_bound_i(batch, N_NODES, g + 1);
    float inv = 1.0f / fmaxf((float)(hi - lo), 1.0f);
    for (int c0 = t; c0 < H; c0 += 384) {
        float a = 0.f;
        for (int c = 0; c < PCH; c++) a += ppool[(size_t)(g * PCH + c) * H + c0];
        row[c0] = a * inv;
    }
    __syncthreads();
    float acc = bc1[t];
    for (int k = 0; k < H; k++) acc += row[k] * wc1[(size_t)k * H2 + t];
    z[g * H2 + t] = fmaxf(acc, 0.f);
}

__global__ void mlp2(const float* __restrict__ z, const float* __restrict__ w,
                     const float* __restrict__ b, float* __restrict__ out) {
    int idx = blockIdx.x * blockDim.x + threadIdx.x;
    if (idx >= NG * NC) return;
    int gg = idx / NC, c = idx % NC;
    const float* zp = z + (size_t)gg * H2;
    float acc = b[c];
    for (int k = 0; k < H2; k++) acc += zp[k] * w[(size_t)k * NC + c];
    out[idx] = acc;
}

// ---------------- launch ----------------
extern "C" void kernel_launch(void* const* d_in, const int* in_sizes, int n_in,
                              void* d_out, int out_size, void* d_ws, size_t ws_size,
                              hipStream_t stream) {
    (void)d_ws; (void)ws_size;
    const float* x     = (const float*)d_in[0];
    const int*   ei    = (const int*)d_in[1];
    const int*   batch = (const int*)d_in[2];
    const float* w1  = (const float*)d_in[3];  const float* b1  = (const float*)d_in[4];
    const float* w2  = (const float*)d_in[5];  const float* b2  = (const float*)d_in[6];
    const float* w3  = (const float*)d_in[7];  const float* b3  = (const float*)d_in[8];
    const float* wg1 = (const float*)d_in[9];  const float* as1 = (const float*)d_in[10];
    const float* ad1 = (const float*)d_in[11]; const float* bg1 = (const float*)d_in[12];
    const float* wg2 = (const float*)d_in[13]; const float* as2 = (const float*)d_in[14];
    const float* ad2 = (const float*)d_in[15]; const float* bg2 = (const float*)d_in[16];
    const float* wc1 = (const float*)d_in[17]; const float* bc1 = (const float*)d_in[18];
    const float* wc2 = (const float*)d_in[19]; const float* bc2 = (const float*)d_in[20];

    const int* srcp = ei;            // edge_index[0]
    const int* dstp = ei + N_EDGES;  // edge_index[1]

    float *bufB, *dinv, *aS, *aD, *ppool, *zb;
    _Float16 *ah, *ch, *wh;
    int *degi, *bsum, *boff, *cursor, *rowptr, *csrsrc;
    hipGetSymbolAddress((void**)&bufB,   HIP_SYMBOL(g_bufB));
    hipGetSymbolAddress((void**)&ah,     HIP_SYMBOL(g_ah));
    hipGetSymbolAddress((void**)&ch,     HIP_SYMBOL(g_ch));
    hipGetSymbolAddress((void**)&wh,     HIP_SYMBOL(g_wh));
    hipGetSymbolAddress((void**)&dinv,   HIP_SYMBOL(g_dinv));
    hipGetSymbolAddress((void**)&degi,   HIP_SYMBOL(g_degi));
    hipGetSymbolAddress((void**)&bsum,   HIP_SYMBOL(g_bsum));
    hipGetSymbolAddress((void**)&boff,   HIP_SYMBOL(g_boff));
    hipGetSymbolAddress((void**)&cursor, HIP_SYMBOL(g_cursor));
    hipGetSymbolAddress((void**)&rowptr, HIP_SYMBOL(g_rowptr));
    hipGetSymbolAddress((void**)&csrsrc, HIP_SYMBOL(g_csrsrc));
    hipGetSymbolAddress((void**)&aS,     HIP_SYMBOL(g_aS));
    hipGetSymbolAddress((void**)&aD,     HIP_SYMBOL(g_aD));
    hipGetSymbolAddress((void**)&ppool,  HIP_SYMBOL(g_ppool));
    hipGetSymbolAddress((void**)&zb,     HIP_SYMBOL(g_zb));

    auto cdiv = [](int a, int b) { return (a + b - 1) / b; };
    int ggrid = 8 * cdiv(cdiv(N_NODES, 128), 8) * (H / 128);   // 2352
    size_t HH = (size_t)H * H;

    // ---- weight transpose+cast, one launch, off the critical path ----
    split_wT4<<<cdiv(4*H*H,256),256,0,stream>>>(w2, w3, wg1, wg2, wh);

    // ---- CSR build (hierarchical scan; r12's 1-block scan was serial) ----
    fill_i32<<<cdiv(N_NODES,256),256,0,stream>>>(degi, N_NODES, 0);
    count_deg<<<cdiv(N_EDGES,256),256,0,stream>>>(dstp, degi);
    scan1<<<NSB,256,0,stream>>>(degi, bsum);
    scan2<<<1,256,0,stream>>>(bsum, boff, rowptr);
    scan3<<<NSB,256,0,stream>>>(degi, boff, rowptr, cursor, dinv);
    bin_edges<<<cdiv(N_EDGES,256),256,0,stream>>>(srcp, dstp, cursor, csrsrc);

    // ---- GCN1 (K=3 GEMM stays fp32 vector math, fp16 out) ----
    gemm_k3<<<cdiv(N_NODES*H,256),256,0,stream>>>(x, w1, ch);
    gcn_gather<<<N_NODES,192,0,stream>>>(rowptr, csrsrc, ch, dinv, b1, ah);

    // ---- GCN2 ----
    gemm_f16<<<ggrid,256,0,stream>>>(ah, wh + 0*HH, ch, N_NODES,
                                     (const float*)nullptr, (const float*)nullptr,
                                     (float*)nullptr, (float*)nullptr);
    gcn_gather<<<N_NODES,192,0,stream>>>(rowptr, csrsrc, ch, dinv, b2, ah);

    // ---- GCN3 ----
    gemm_f16<<<ggrid,256,0,stream>>>(ah, wh + 1*HH, ch, N_NODES,
                                     (const float*)nullptr, (const float*)nullptr,
                                     (float*)nullptr, (float*)nullptr);
    gcn_gather<<<N_NODES,192,0,stream>>>(rowptr, csrsrc, ch, dinv, b3, ah);

    // ---- GAT1 (alpha fused into GEMM epilogue) ----
    gemm_f16<<<ggrid,256,0,stream>>>(ah, wh + 2*HH, ch, N_NODES, as1, ad1, aS, aD);
    gat_gather<<<N_NODES,192,0,stream>>>(rowptr, csrsrc, ch, aS, aD, bg1,
                                         (float*)nullptr, ah, 1);

    // ---- GAT2 (no relu; fp32 out for pooling) ----
    gemm_f16<<<ggrid,256,0,stream>>>(ah, wh + 3*HH, ch, N_NODES, as2, ad2, aS, aD);
    gat_gather<<<N_NODES,192,0,stream>>>(rowptr, csrsrc, ch, aS, aD, bg2,
                                         bufB, (_Float16*)nullptr, 0);

    // ---- pool (two-stage; stage-2 fused with mlp1) + classifier ----
    pool_partial<<<NG*PCH,192,0,stream>>>(batch, bufB, ppool);
    pool_mlp1<<<NG,384,0,stream>>>(batch, ppool, wc1, bc1, zb);
    mlp2<<<cdiv(NG*NC,64),64,0,stream>>>(zb, wc2, bc2, (float*)d_out);
}